// Round 10
// baseline (394.440 us; speedup 1.0000x reference)
//
#include <hip/hip_runtime.h>
#include <cmath>

#define CC 128
#define HH 64
#define WWI 64
#define LL 1024
#define NB 16
#define MM 1152          // 128 channels * 9 taps
#define KC 384           // concat K for bf16x3 T-GEMM
#define TPD 1156         // 34*34 padded dim

// per-batch slab layout (floats):
#define SLAB      2977808ul
#define OFF_TP    0
#define OFF_S3T   0
#define OFF_W     0
#define OFF_S2    1336336
#define OFF_SCORET 1336336
#define OFF_POOL  2384912
#define OFF_N2    2974736
#define OFF_BNORM 2975760
#define OFF_VALID 2976784

// halo geometry (zeroing folded into k_gemm_T epilogue)
#define NHROW 132
#define NH1 (NHROW * TPD)
#define NHALO (NH1 + 1024 * NHROW)

typedef __bf16 bf16x8 __attribute__((ext_vector_type(8)));
typedef __bf16 bf16x4 __attribute__((ext_vector_type(4)));
typedef float f32x4 __attribute__((ext_vector_type(4)));

#define GLDS(g, l) __builtin_amdgcn_global_load_lds( \
    (const __attribute__((address_space(1))) unsigned int*)(const void*)(g), \
    (__attribute__((address_space(3))) unsigned int*)(void*)(l), 16, 0, 0)

// ---- downsample + transpose (LDS tile) + bf16 hi/lo concat + fused n2 ----
__global__ __launch_bounds__(256) void k_prep(const float* __restrict__ f_o,
                                              const float* __restrict__ b_o,
                                              float* __restrict__ ws,
                                              int b0, int aff) {
    int bz, uy;
    if (aff) { int g = blockIdx.x; bz = g & 15; uy = g >> 4; }
    else     { bz = blockIdx.y; uy = blockIdx.x; }
    int gb = b0 + bz;
    __shared__ float lf[128 * 33];
    __shared__ float lb[128 * 33];
    __shared__ float red[8 * 32];
    int tid = threadIdx.x;
    int ux = tid & 31, co = tid >> 5;
    size_t pix = (size_t)(2 * uy) * WWI + 2 * ux;
    const float* fbp = f_o + (size_t)gb * CC * HH * WWI + pix;
    const float* bbp = b_o + (size_t)gb * CC * HH * WWI + pix;
#pragma unroll
    for (int pass = 0; pass < 16; pass++) {
        int c = pass * 8 + co;
        lf[c * 33 + ux] = fbp[(size_t)c * HH * WWI];
        lb[c * 33 + ux] = bbp[(size_t)c * HH * WWI];
    }
    __syncthreads();
    int ux2 = tid >> 3, cg = (tid & 7) * 16;
    int u = uy * 32 + ux2;
    __bf16* bcat = (__bf16*)(ws + (size_t)bz * SLAB + OFF_POOL) + (size_t)u * KC;
    __bf16* fcat = bcat + 393216;
    float s2 = 0.f;
#pragma unroll
    for (int k = 0; k < 16; k++) {
        int c = cg + k;
        float fv = lf[c * 33 + ux2];
        float bv = lb[c * 33 + ux2];
        __bf16 fhi = (__bf16)fv; __bf16 flo = (__bf16)(fv - (float)fhi);
        __bf16 bhi = (__bf16)bv; __bf16 blo = (__bf16)(bv - (float)bhi);
        bcat[c] = bhi; bcat[128 + c] = bhi; bcat[256 + c] = blo;
        fcat[c] = fhi; fcat[128 + c] = flo; fcat[256 + c] = fhi;
        s2 += bv * bv;
    }
    red[(tid & 7) * 32 + ux2] = s2;
    __syncthreads();
    if (tid < 32) {
        float s = 0.f;
#pragma unroll
        for (int k = 0; k < 8; k++) s += red[k * 32 + tid];
        ws[(size_t)bz * SLAB + OFF_N2 + uy * 32 + tid] = s;
    }
}

__global__ __launch_bounds__(256) void k_bnorm_valid(float* __restrict__ ws,
                                                     const float* __restrict__ mask,
                                                     int b0, int aff) {
    int g = blockIdx.x;
    int bz, pc;
    if (aff) { bz = g & 15; pc = g >> 4; }
    else     { bz = g >> 2; pc = g & 3; }
    int p = pc * 256 + threadIdx.x;
    int gb = b0 + bz;
    int py = p >> 5, px = p & 31;
    const float* mb = mask + (size_t)gb * HH * WWI;
    const float* n2 = ws + (size_t)bz * SLAB + OFF_N2;
    float s = 0.f, msum = 0.f;
#pragma unroll
    for (int dy = -1; dy <= 1; dy++) {
#pragma unroll
        for (int dx = -1; dx <= 1; dx++) {
            int py2 = py + dy, px2 = px + dx;
            if ((unsigned)py2 < 32u && (unsigned)px2 < 32u) {
                s    += n2[(py2 << 5) | px2];
                msum += mb[(2 * py2) * WWI + 2 * px2];
            }
        }
    }
    ws[(size_t)bz * SLAB + OFF_BNORM + p] = fmaxf(sqrtf(s), 1e-4f);
    ws[(size_t)bz * SLAB + OFF_VALID + p] = (msum == 0.0f) ? 1.0f : 0.0f;
}

__device__ __forceinline__ int halo_idx(int k) {
    if (k < 34) return k;
    if (k < 68) return 1122 + (k - 34);
    if (k < 100) return 34 * (k - 100 + 33);
    return 34 * (k - 132 + 33) + 33;
}

// ---- 128x128-tile BK=64 MFMA GEMM core (depth-2 counted vmcnt) ----
template<int KTOT>
__device__ __forceinline__ void gemm_core(const __bf16* __restrict__ Ab,
                                          const __bf16* __restrict__ Bb,
                                          int lda, int ldb, int m0, int n0,
                                          __bf16* As, __bf16* Bs,
                                          f32x4 acc[4][4]) {
    int t = threadIdx.x;
    int lane = t & 63, w = t >> 6;
    int rsub = lane >> 3;
    int g8   = ((lane & 7) ^ (rsub & 7)) * 8;
    int lm = lane & 15, kgf = lane >> 4;
    int wm = (w & 1) * 64, wn = (w >> 1) * 64;

#define ISSUE(kt, buf) do {                                                   \
    int k0_ = (kt) * 64;                                                      \
    _Pragma("unroll")                                                         \
    for (int ci = 0; ci < 4; ci++) {                                          \
        int rb = ci * 32 + w * 8;                                             \
        int r  = rb + rsub;                                                   \
        GLDS(Ab + (size_t)(m0 + r) * lda + k0_ + g8, &As[(buf) + rb * 64]);   \
        GLDS(Bb + (size_t)(n0 + r) * ldb + k0_ + g8, &Bs[(buf) + rb * 64]);   \
    } } while (0)

#define COMPUTE(curoff) do {                                                  \
    _Pragma("unroll")                                                         \
    for (int s2 = 0; s2 < 2; s2++) {                                          \
        bf16x8 af[4], bfr[4];                                                 \
        _Pragma("unroll")                                                     \
        for (int i = 0; i < 4; i++)                                           \
            af[i] = *(const bf16x8*)&As[(curoff) + (wm + i * 16 + lm) * 64 +  \
                                        (((s2 * 4 + kgf) ^ (lm & 7)) * 8)];   \
        _Pragma("unroll")                                                     \
        for (int j = 0; j < 4; j++)                                           \
            bfr[j] = *(const bf16x8*)&Bs[(curoff) + (wn + j * 16 + lm) * 64 + \
                                         (((s2 * 4 + kgf) ^ (lm & 7)) * 8)];  \
        _Pragma("unroll")                                                     \
        for (int i = 0; i < 4; i++)                                           \
            _Pragma("unroll")                                                 \
            for (int j = 0; j < 4; j++)                                       \
                acc[i][j] = __builtin_amdgcn_mfma_f32_16x16x32_bf16(          \
                    af[i], bfr[j], acc[i][j], 0, 0, 0);                       \
    } } while (0)

    const int NIT = KTOT / 64;

    ISSUE(0, 0);
    ISSUE(1, 8192);

#pragma unroll 2
    for (int it = 0; it < NIT - 2; it++) {
        int cur = (it & 1) * 8192;
        asm volatile("s_waitcnt vmcnt(8)" ::: "memory");
        __builtin_amdgcn_sched_barrier(0);
        __builtin_amdgcn_s_barrier();
        COMPUTE(cur);
        __builtin_amdgcn_s_barrier();
        ISSUE(it + 2, cur);
    }
    asm volatile("s_waitcnt vmcnt(8)" ::: "memory");
    __builtin_amdgcn_sched_barrier(0);
    __builtin_amdgcn_s_barrier();
    COMPUTE(((NIT - 2) & 1) * 8192);
    __builtin_amdgcn_s_barrier();
    asm volatile("s_waitcnt vmcnt(0)" ::: "memory");
    __builtin_amdgcn_sched_barrier(0);
    __builtin_amdgcn_s_barrier();
    COMPUTE(((NIT - 1) & 1) * 8192);

#undef ISSUE
#undef COMPUTE
}

// ---- T GEMM (bf16x3 == fp32), padded-4D epilogue + folded halo-zero ----
__global__ __launch_bounds__(256) void k_gemm_T_mfma(float* __restrict__ ws, int swz) {
    int bz, m0, n0;
    if (swz) {
        bz = blockIdx.x + 8 * (blockIdx.z & 1);
        m0 = blockIdx.y * 128;
        n0 = (blockIdx.z >> 1) * 128;
    } else {
        bz = blockIdx.z; m0 = blockIdx.y * 128; n0 = blockIdx.x * 128;
    }
    const __bf16* Ab = (const __bf16*)(ws + (size_t)bz * SLAB + OFF_POOL);
    const __bf16* Bb = Ab + 393216;
    float* Tp = ws + (size_t)bz * SLAB + OFF_TP;
    __shared__ __align__(16) __bf16 As[2 * 128 * 64];
    __shared__ __align__(16) __bf16 Bs[2 * 128 * 64];
    f32x4 acc[4][4];
#pragma unroll
    for (int i = 0; i < 4; i++)
#pragma unroll
        for (int j = 0; j < 4; j++) acc[i][j] = (f32x4)0.0f;
    gemm_core<KC>(Ab, Bb, KC, KC, m0, n0, As, Bs, acc);
    int lane = threadIdx.x & 63, w = threadIdx.x >> 6;
    int lm = lane & 15, kgf = lane >> 4;
    int wm = (w & 1) * 64, wn = (w >> 1) * 64;
#pragma unroll
    for (int i = 0; i < 4; i++) {
#pragma unroll
        for (int r = 0; r < 4; r++) {
            int m = m0 + wm + i * 16 + kgf * 4 + r;
            float* dst = Tp + (size_t)(((m >> 5) + 1) * 34 + (m & 31) + 1) * TPD;
#pragma unroll
            for (int j = 0; j < 4; j++) {
                int v = n0 + wn + j * 16 + lm;
                dst[((v >> 5) + 1) * 34 + (v & 31) + 1] = acc[i][j][r];
            }
        }
    }
    // folded zerohalo: the 64 blocks of this batch cooperatively zero the
    // NHALO halo cells (disjoint from interior stores; s12 runs next launch)
    int cb = (m0 >> 7) * 8 + (n0 >> 7);            // [0,64) per batch
    for (int h = cb * 256 + (int)threadIdx.x; h < NHALO; h += 64 * 256) {
        if (h < NH1) {
            int R = halo_idx(h / TPD);
            Tp[(size_t)R * TPD + (h % TPD)] = 0.f;
        } else {
            int t2 = h - NH1;
            int ir = t2 / NHROW;
            int R  = 34 * (1 + (ir >> 5)) + 1 + (ir & 31);
            int C  = halo_idx(t2 % NHROW);
            Tp[(size_t)R * TPD + C] = 0.f;
        }
    }
}

// ---- W GEMM, 288x256 tile, 512 threads / 8 waves, grid = 256 = ONE round
// 1152 = 4*288 exact; 4M x 4N x 16 batches = 256 blocks = 1 block/CU with
// zero dispatch tail (the 384-block variants paid 2 scheduling rounds).
// Pipeline = R5's proven issue-early: stage kt+1 fully at top of kt,
// vmcnt(0)+barrier once per K-tile boundary. Wave tile 144x64, acc[9][4].
__global__ __launch_bounds__(512, 2) void k_gemm_W288(float* __restrict__ ws) {
    int d = blockIdx.x;                 // 256 blocks, linear decode
    int bz  = d >> 4;
    int t16 = d & 15;
    int m0 = (t16 >> 2) * 288;          // 4 M-tiles exact
    int n0 = (t16 & 3) * 256;
    const __bf16* Ab = (const __bf16*)(ws + (size_t)bz * SLAB + OFF_POOL);
    const __bf16* Bb = (const __bf16*)(ws + (size_t)bz * SLAB + OFF_SCORET);
    __bf16* Wb = (__bf16*)(ws + (size_t)bz * SLAB + OFF_W);
    __shared__ __align__(16) __bf16 As[2 * 288 * 64];   // 72 KiB
    __shared__ __align__(16) __bf16 Bs[2 * 256 * 64];   // 64 KiB

    int t = threadIdx.x;
    int lane = t & 63, w = t >> 6;
    int rsub = lane >> 3;
    int g8   = ((lane & 7) ^ (rsub & 7)) * 8;
    int lm = lane & 15, kgf = lane >> 4;
    int wr = (w >> 2) * 144;            // wave M-offset (0/144)
    int wc = (w & 3) * 64;              // wave N-offset (0/64/128/192)

    f32x4 acc[9][4];
#pragma unroll
    for (int i = 0; i < 9; i++)
#pragma unroll
        for (int j = 0; j < 4; j++) acc[i][j] = (f32x4)0.0f;

    // A: 288 rows = 4 full wave-rounds (256) + rows 256-287 by waves 0-3.
    // B: 256 rows = 4 full wave-rounds. 9 (or 10) GLDS per thread.
#define WSTAGE(nbA, nbB, k1_) do {                                            \
    _Pragma("unroll")                                                         \
    for (int ci = 0; ci < 4; ci++) {                                          \
        int rb = ci * 64 + w * 8;                                             \
        GLDS(Ab + (size_t)(m0 + rb + rsub) * LL + (k1_) + g8,                 \
             &As[(nbA) + rb * 64]);                                           \
    }                                                                         \
    if (w < 4) {                                                              \
        int rb = 256 + w * 8;                                                 \
        GLDS(Ab + (size_t)(m0 + rb + rsub) * LL + (k1_) + g8,                 \
             &As[(nbA) + rb * 64]);                                           \
    }                                                                         \
    _Pragma("unroll")                                                         \
    for (int ci = 0; ci < 4; ci++) {                                          \
        int rb = ci * 64 + w * 8;                                             \
        GLDS(Bb + (size_t)(n0 + rb + rsub) * LL + (k1_) + g8,                 \
             &Bs[(nbB) + rb * 64]);                                           \
    } } while (0)

    WSTAGE(0, 0, 0);
    asm volatile("s_waitcnt vmcnt(0)" ::: "memory");
    __builtin_amdgcn_sched_barrier(0);
    __builtin_amdgcn_s_barrier();

#pragma unroll 2
    for (int kt = 0; kt < 16; kt++) {
        int boA = (kt & 1) * 18432, boB = (kt & 1) * 16384;
        int nbA = boA ^ 18432, nbB = boB ^ 16384;
        if (kt < 15) WSTAGE(nbA, nbB, (kt + 1) * 64);
#pragma unroll
        for (int ks = 0; ks < 2; ks++) {
            bf16x8 af[9], bfr[4];
            int ko = ((ks * 4 + kgf) ^ (lm & 7)) * 8;
#pragma unroll
            for (int mi = 0; mi < 9; mi++)
                af[mi] = *(const bf16x8*)&As[boA + (wr + mi * 16 + lm) * 64 + ko];
#pragma unroll
            for (int nj = 0; nj < 4; nj++)
                bfr[nj] = *(const bf16x8*)&Bs[boB + (wc + nj * 16 + lm) * 64 + ko];
            __builtin_amdgcn_s_setprio(1);
#pragma unroll
            for (int mi = 0; mi < 9; mi++)
#pragma unroll
                for (int nj = 0; nj < 4; nj++)
                    acc[mi][nj] = __builtin_amdgcn_mfma_f32_16x16x32_bf16(
                        af[mi], bfr[nj], acc[mi][nj], 0, 0, 0);
            __builtin_amdgcn_s_setprio(0);
        }
        if (kt < 15) {
            asm volatile("s_waitcnt vmcnt(0)" ::: "memory");
            __builtin_amdgcn_sched_barrier(0);
            __builtin_amdgcn_s_barrier();
        }
    }

#undef WSTAGE

#pragma unroll
    for (int mf = 0; mf < 9; mf++) {
#pragma unroll
        for (int r = 0; r < 4; r++) {
            int m = m0 + wr + mf * 16 + kgf * 4 + r;   // always < 1152
            __bf16* dst = Wb + (size_t)m * LL + n0 + wc + lm;
#pragma unroll
            for (int nj = 0; nj < 4; nj++)
                dst[nj * 16] = (__bf16)acc[mf][nj][r];
        }
    }
}

// ---- W[m,q] GEMM 128-tile fallback (Gc<16 path) ----
__global__ __launch_bounds__(256) void k_gemm_W_mfma(float* __restrict__ ws, int swz) {
    int bz, m0, n0;
    if (swz) {
        bz = blockIdx.x + 8 * (blockIdx.z & 1);
        m0 = blockIdx.y * 128;
        n0 = (blockIdx.z >> 1) * 128;
    } else {
        bz = blockIdx.z; m0 = blockIdx.y * 128; n0 = blockIdx.x * 128;
    }
    const __bf16* Ab = (const __bf16*)(ws + (size_t)bz * SLAB + OFF_POOL);
    const __bf16* Bb = (const __bf16*)(ws + (size_t)bz * SLAB + OFF_SCORET);
    __bf16* Wb = (__bf16*)(ws + (size_t)bz * SLAB + OFF_W);
    __shared__ __align__(16) __bf16 As[2 * 128 * 64];
    __shared__ __align__(16) __bf16 Bs[2 * 128 * 64];
    f32x4 acc[4][4];
#pragma unroll
    for (int i = 0; i < 4; i++)
#pragma unroll
        for (int j = 0; j < 4; j++) acc[i][j] = (f32x4)0.0f;
    gemm_core<LL>(Ab, Bb, LL, LL, m0, n0, As, Bs, acc);
    int lane = threadIdx.x & 63, w = threadIdx.x >> 6;
    int lm = lane & 15, kgf = lane >> 4;
    int wm = (w & 1) * 64, wn = (w >> 1) * 64;
#pragma unroll
    for (int i = 0; i < 4; i++) {
#pragma unroll
        for (int r = 0; r < 4; r++) {
            int m = m0 + wm + i * 16 + kgf * 4 + r;
            __bf16* dst = Wb + (size_t)m * LL + n0 + wn + lm;
#pragma unroll
            for (int j = 0; j < 4; j++)
                dst[j * 16] = (__bf16)acc[i][j][r];
        }
    }
}

// ---- fused st1+st2 (padded T, 9 unconditional loads per element) ----
__global__ __launch_bounds__(256) void k_s12(float* __restrict__ ws, int aff) {
    int bz, i0;
    if (aff) { int g = blockIdx.x; bz = g & 15; i0 = (g >> 4) * 8; }
    else     { bz = blockIdx.y; i0 = blockIdx.x * 8; }
    const float* Tp = ws + (size_t)bz * SLAB + OFF_TP;
    const float* bn = ws + (size_t)bz * SLAB + OFF_BNORM;
    float* S2 = ws + (size_t)bz * SLAB + OFF_S2;
    __shared__ float Dsh[10][1024];
    int tid = threadIdx.x;
    for (int rl = 0; rl < 10; rl++) {
        int r = i0 - 1 + rl;
        if ((unsigned)r >= 1024u) continue;
        float invr = 1.0f / bn[r];
        size_t rbase = (size_t)(((r >> 5) + 1) * 34 + (r & 31) + 1) * TPD;
#pragma unroll
        for (int so = 0; so < 4; so++) {
            int s = so * 256 + tid;
            const float* cb = Tp + rbase + ((s >> 5) + 1) * 34 + (s & 31) + 1;
            float d = 0.f;
#pragma unroll
            for (int dy = -1; dy <= 1; dy++)
#pragma unroll
                for (int dx = -1; dx <= 1; dx++)
                    d += cb[dy * (34 * TPD + 34) + dx * (TPD + 1)];
            Dsh[rl][s] = d * invr;
        }
    }
    __syncthreads();
#pragma unroll
    for (int il = 0; il < 8; il++) {
        int i = i0 + il;
        float* orow = S2 + (size_t)i * LL;
#pragma unroll
        for (int jo = 0; jo < 4; jo++) {
            int j = jo * 256 + tid;
            float acc = 0.f;
#pragma unroll
            for (int k1 = -1; k1 <= 1; k1++) {
                int r = i + k1, s = j + k1;
                if ((unsigned)r < 1024u && (unsigned)s < 1024u)
                    acc += Dsh[il + 1 + k1][s];
            }
            orow[j] = acc;
        }
    }
}

// ---- second diag_fuse (sigma-space) fused with transpose: S3T[q][p] ----
__global__ __launch_bounds__(256) void k_st3t(float* __restrict__ ws, int aff) {
    int bz, p0, q0;
    if (aff) {
        int g = blockIdx.x; bz = g & 15;
        int tile = g >> 4; p0 = (tile >> 4) * 64; q0 = (tile & 15) * 64;
    } else {
        bz = blockIdx.z; p0 = blockIdx.y * 64; q0 = blockIdx.x * 64;
    }
    const float* ib = ws + (size_t)bz * SLAB + OFF_S2;
    float* ob = ws + (size_t)bz * SLAB + OFF_S3T;
    __shared__ float tile[64][65];
    int t = threadIdx.x;
#pragma unroll
    for (int it = 0; it < 16; it++) {
        int e = it * 256 + t;
        int pl = e >> 6, ql = e & 63;
        int p = p0 + pl, q = q0 + ql;
        int sp = ((p & 31) << 5) | (p >> 5);
        int sq = ((q & 31) << 5) | (q >> 5);
        float acc = 0.f;
#pragma unroll
        for (int k = -1; k <= 1; k++) {
            int tp = sp + k, tq = sq + k;
            if ((unsigned)tp < 1024u && (unsigned)tq < 1024u) {
                int row = ((tp & 31) << 5) | (tp >> 5);
                int col = ((tq & 31) << 5) | (tq >> 5);
                acc += ib[(size_t)row * LL + col];
            }
        }
        tile[pl][ql] = acc;
    }
    __syncthreads();
#pragma unroll
    for (int it = 0; it < 16; it++) {
        int e = it * 256 + t;
        int ql = e >> 6, pl = e & 63;
        ob[(size_t)(q0 + ql) * LL + p0 + pl] = tile[pl][ql];
    }
}

// ---- row softmax on S3T, writes bf16 scoreT[q][p] ----
__global__ __launch_bounds__(256) void k_softmax_bf(float* __restrict__ ws, int aff) {
    int bz, q;
    if (aff) {
        int g = blockIdx.x; bz = g & 15;
        q = (g >> 4) * 4 + (threadIdx.x >> 6);
    } else {
        bz = blockIdx.z;
        q = blockIdx.x * 4 + (threadIdx.x >> 6);
    }
    int lane = threadIdx.x & 63;
    const float* row = ws + (size_t)bz * SLAB + OFF_S3T + (size_t)q * LL;
    const float* vb  = ws + (size_t)bz * SLAB + OFF_VALID;
    __bf16* orow = (__bf16*)(ws + (size_t)bz * SLAB + OFF_SCORET) + (size_t)q * LL;

    float4 v[4], vl[4];
#pragma unroll
    for (int i = 0; i < 4; i++) {
        int p = lane * 4 + i * 256;
        float4 s = *(const float4*)(row + p);
        float4 m = *(const float4*)(vb + p);
        v[i] = {s.x * m.x, s.y * m.y, s.z * m.z, s.w * m.w};
        vl[i] = m;
    }
    float mx = -1e30f;
#pragma unroll
    for (int i = 0; i < 4; i++)
        mx = fmaxf(mx, fmaxf(fmaxf(v[i].x, v[i].y), fmaxf(v[i].z, v[i].w)));
#pragma unroll
    for (int k = 1; k < 64; k <<= 1)
        mx = fmaxf(mx, __shfl_xor(mx, k, 64));
    float sum = 0.f;
    float4 e[4];
#pragma unroll
    for (int i = 0; i < 4; i++) {
        e[i].x = __expf(10.f * (v[i].x - mx));
        e[i].y = __expf(10.f * (v[i].y - mx));
        e[i].z = __expf(10.f * (v[i].z - mx));
        e[i].w = __expf(10.f * (v[i].w - mx));
        sum += e[i].x + e[i].y + e[i].z + e[i].w;
    }
#pragma unroll
    for (int k = 1; k < 64; k <<= 1)
        sum += __shfl_xor(sum, k, 64);
    float inv = 1.0f / sum;
#pragma unroll
    for (int i = 0; i < 4; i++) {
        bf16x4 o;
        o[0] = (__bf16)(e[i].x * inv * vl[i].x);
        o[1] = (__bf16)(e[i].y * inv * vl[i].y);
        o[2] = (__bf16)(e[i].z * inv * vl[i].z);
        o[3] = (__bf16)(e[i].w * inv * vl[i].w);
        *(bf16x4*)(orow + lane * 4 + i * 256) = o;
    }
}

// ---- coalesced makeA: block per (channel, batch); LDS image tile ----
__global__ __launch_bounds__(256) void k_makeA(const float* __restrict__ b_o,
                                               float* __restrict__ ws,
                                               int b0, int aff) {
    int c, bz;
    if (aff) { int g = blockIdx.x; bz = g & 15; c = g >> 4; }
    else     { c = blockIdx.x; bz = blockIdx.y; }
    int gb = b0 + bz;
    __shared__ float img[64][65];
    int t = threadIdx.x;
    const float4* src = (const float4*)(b_o + (size_t)(gb * CC + c) * HH * WWI);
#pragma unroll
    for (int it = 0; it < 4; it++) {
        int idx = it * 256 + t;
        float4 v = src[idx];
        int row = idx >> 4, col4 = (idx & 15) * 4;
        img[row][col4] = v.x; img[row][col4 + 1] = v.y;
        img[row][col4 + 2] = v.z; img[row][col4 + 3] = v.w;
    }
    __syncthreads();
    __bf16* Ab = (__bf16*)(ws + (size_t)bz * SLAB + OFF_POOL) + (size_t)c * 9 * LL;
    int py = t >> 3, px4 = (t & 7) * 4;
#pragma unroll
    for (int jy = 0; jy < 3; jy++) {
        int row = 2 * py + jy - 1;
        bool rok = (unsigned)row < 64u;
#pragma unroll
        for (int jx = 0; jx < 3; jx++) {
            bf16x4 o;
#pragma unroll
            for (int e = 0; e < 4; e++) {
                int col = 2 * (px4 + e) + jx - 1;
                float v = (rok && (unsigned)col < 64u) ? img[rok ? row : 0][(unsigned)col < 64u ? col : 0] : 0.f;
                o[e] = (__bf16)v;
            }
            *(bf16x4*)(Ab + (size_t)(jy * 3 + jx) * LL + t * 4) = o;
        }
    }
}

// ---- gather: out[c,oy,ox] = 0.25 * sum of <=4 bf16 W taps ----
__global__ __launch_bounds__(256) void k_gather(const float* __restrict__ ws,
                                                float* __restrict__ outp,
                                                int b0, int aff) {
    int t;
    if (aff) {
        int g = blockIdx.x;
        int bz_ = g & 15;
        t = (bz_ << 19) + (g >> 4) * 256 + threadIdx.x;
    } else {
        t = blockIdx.x * 256 + threadIdx.x;
    }
    int ox = t & 63, oy = (t >> 6) & 63, c = (t >> 12) & 127, bz = t >> 19;
    const __bf16* Wb = (const __bf16*)(ws + (size_t)bz * SLAB + OFF_W);
    int qyA = (oy + 1) >> 1;
    int jyA = (oy & 1) ? 0 : 1;
    int vA  = (qyA < 32);
    int qyB = (oy - 1) >> 1;
    int vB  = (oy & 1);
    int qxA = (ox + 1) >> 1;
    int jxA = (ox & 1) ? 0 : 1;
    int uA  = (qxA < 32);
    int qxB = (ox - 1) >> 1;
    int uB  = (ox & 1);
    const __bf16* base = Wb + (size_t)c * 9 * LL;
    float s = 0.f;
    if (vA && uA) s += (float)base[(size_t)(jyA * 3 + jxA) * LL + qyA * 32 + qxA];
    if (vA && uB) s += (float)base[(size_t)(jyA * 3 + 2)   * LL + qyA * 32 + qxB];
    if (vB && uA) s += (float)base[(size_t)(2 * 3 + jxA)   * LL + qyB * 32 + qxA];
    if (vB && uB) s += (float)base[(size_t)(2 * 3 + 2)     * LL + qyB * 32 + qxB];
    outp[((size_t)((b0 + bz) * CC + c) * HH + oy) * WWI + ox] = 0.25f * s;
}

extern "C" void kernel_launch(void* const* d_in, const int* in_sizes, int n_in,
                              void* d_out, int out_size, void* d_ws, size_t ws_size,
                              hipStream_t stream) {
    (void)in_sizes; (void)n_in; (void)out_size;
    const float* f_o  = (const float*)d_in[0];
    const float* b_o  = (const float*)d_in[1];
    const float* mask = (const float*)d_in[2];
    float* out = (float*)d_out;

    int G = (int)(ws_size / (SLAB * sizeof(float)));   // ~11.9 MB per batch slab
    if (G < 1) G = 1;
    if (G > NB) G = NB;
    float* ws = (float*)d_ws;

    for (int b0 = 0; b0 < NB; b0 += G) {
        int Gc = NB - b0 < G ? NB - b0 : G;
        if (Gc == NB) {
            // XCD-affinity path for the chain; W = 288-tile, 1 round, spread
            k_prep<<<dim3(512), 256, 0, stream>>>(f_o, b_o, ws, 0, 1);
            k_bnorm_valid<<<dim3(64), 256, 0, stream>>>(ws, mask, 0, 1);
            k_gemm_T_mfma<<<dim3(8, 8, 16), 256, 0, stream>>>(ws, 1);
            k_s12<<<dim3(2048), 256, 0, stream>>>(ws, 1);
            k_st3t<<<dim3(4096), 256, 0, stream>>>(ws, 1);
            k_softmax_bf<<<dim3(4096), 256, 0, stream>>>(ws, 1);
            k_makeA<<<dim3(2048), 256, 0, stream>>>(b_o, ws, 0, 1);
            k_gemm_W288<<<dim3(256), 512, 0, stream>>>(ws);
            k_gather<<<dim3(32768), 256, 0, stream>>>(ws, out, 0, 1);
        } else {
            k_prep<<<dim3(32, Gc), 256, 0, stream>>>(f_o, b_o, ws, b0, 0);
            k_bnorm_valid<<<dim3(Gc * 4), 256, 0, stream>>>(ws, mask, b0, 0);
            k_gemm_T_mfma<<<dim3(8, 8, Gc), 256, 0, stream>>>(ws, 0);
            k_s12<<<dim3(128, Gc), 256, 0, stream>>>(ws, 0);
            k_st3t<<<dim3(16, 16, Gc), 256, 0, stream>>>(ws, 0);
            k_softmax_bf<<<dim3(256, 1, Gc), 256, 0, stream>>>(ws, 0);
            k_makeA<<<dim3(CC, Gc), 256, 0, stream>>>(b_o, ws, b0, 0);
            k_gemm_W_mfma<<<dim3(8, 9, Gc), 256, 0, stream>>>(ws, 0);
            k_gather<<<dim3(Gc * 2048), 256, 0, stream>>>(ws, out, b0, 0);
        }
    }
}

// Round 11
// 379.705 us; speedup vs baseline: 1.0388x; 1.0388x over previous
//
#include <hip/hip_runtime.h>
#include <cmath>

#define CC 128
#define HH 64
#define WWI 64
#define LL 1024
#define NB 16
#define MM 1152          // 128 channels * 9 taps
#define KC 384           // concat K for bf16x3 T-GEMM
#define TPD 1156         // 34*34 padded dim

// per-batch slab layout (floats):
#define SLAB      2977808ul
#define OFF_TP    0
#define OFF_S3T   0
#define OFF_W     0
#define OFF_S2    1336336
#define OFF_SCORET 1336336
#define OFF_POOL  2384912
#define OFF_N2    2974736
#define OFF_BNORM 2975760
#define OFF_VALID 2976784

// halo geometry (zeroing folded into k_gemm_T epilogue)
#define NHROW 132
#define NH1 (NHROW * TPD)
#define NHALO (NH1 + 1024 * NHROW)

typedef __bf16 bf16x8 __attribute__((ext_vector_type(8)));
typedef __bf16 bf16x4 __attribute__((ext_vector_type(4)));
typedef float f32x4 __attribute__((ext_vector_type(4)));

#define GLDS(g, l) __builtin_amdgcn_global_load_lds( \
    (const __attribute__((address_space(1))) unsigned int*)(const void*)(g), \
    (__attribute__((address_space(3))) unsigned int*)(void*)(l), 16, 0, 0)

// ---- downsample + transpose (LDS tile) + bf16 hi/lo concat + fused n2 ----
__global__ __launch_bounds__(256) void k_prep(const float* __restrict__ f_o,
                                              const float* __restrict__ b_o,
                                              float* __restrict__ ws,
                                              int b0, int aff) {
    int bz, uy;
    if (aff) { int g = blockIdx.x; bz = g & 15; uy = g >> 4; }
    else     { bz = blockIdx.y; uy = blockIdx.x; }
    int gb = b0 + bz;
    __shared__ float lf[128 * 33];
    __shared__ float lb[128 * 33];
    __shared__ float red[8 * 32];
    int tid = threadIdx.x;
    int ux = tid & 31, co = tid >> 5;
    size_t pix = (size_t)(2 * uy) * WWI + 2 * ux;
    const float* fbp = f_o + (size_t)gb * CC * HH * WWI + pix;
    const float* bbp = b_o + (size_t)gb * CC * HH * WWI + pix;
#pragma unroll
    for (int pass = 0; pass < 16; pass++) {
        int c = pass * 8 + co;
        lf[c * 33 + ux] = fbp[(size_t)c * HH * WWI];
        lb[c * 33 + ux] = bbp[(size_t)c * HH * WWI];
    }
    __syncthreads();
    int ux2 = tid >> 3, cg = (tid & 7) * 16;
    int u = uy * 32 + ux2;
    __bf16* bcat = (__bf16*)(ws + (size_t)bz * SLAB + OFF_POOL) + (size_t)u * KC;
    __bf16* fcat = bcat + 393216;
    float s2 = 0.f;
#pragma unroll
    for (int k = 0; k < 16; k++) {
        int c = cg + k;
        float fv = lf[c * 33 + ux2];
        float bv = lb[c * 33 + ux2];
        __bf16 fhi = (__bf16)fv; __bf16 flo = (__bf16)(fv - (float)fhi);
        __bf16 bhi = (__bf16)bv; __bf16 blo = (__bf16)(bv - (float)bhi);
        bcat[c] = bhi; bcat[128 + c] = bhi; bcat[256 + c] = blo;
        fcat[c] = fhi; fcat[128 + c] = flo; fcat[256 + c] = fhi;
        s2 += bv * bv;
    }
    red[(tid & 7) * 32 + ux2] = s2;
    __syncthreads();
    if (tid < 32) {
        float s = 0.f;
#pragma unroll
        for (int k = 0; k < 8; k++) s += red[k * 32 + tid];
        ws[(size_t)bz * SLAB + OFF_N2 + uy * 32 + tid] = s;
    }
}

__global__ __launch_bounds__(256) void k_bnorm_valid(float* __restrict__ ws,
                                                     const float* __restrict__ mask,
                                                     int b0, int aff) {
    int g = blockIdx.x;
    int bz, pc;
    if (aff) { bz = g & 15; pc = g >> 4; }
    else     { bz = g >> 2; pc = g & 3; }
    int p = pc * 256 + threadIdx.x;
    int gb = b0 + bz;
    int py = p >> 5, px = p & 31;
    const float* mb = mask + (size_t)gb * HH * WWI;
    const float* n2 = ws + (size_t)bz * SLAB + OFF_N2;
    float s = 0.f, msum = 0.f;
#pragma unroll
    for (int dy = -1; dy <= 1; dy++) {
#pragma unroll
        for (int dx = -1; dx <= 1; dx++) {
            int py2 = py + dy, px2 = px + dx;
            if ((unsigned)py2 < 32u && (unsigned)px2 < 32u) {
                s    += n2[(py2 << 5) | px2];
                msum += mb[(2 * py2) * WWI + 2 * px2];
            }
        }
    }
    ws[(size_t)bz * SLAB + OFF_BNORM + p] = fmaxf(sqrtf(s), 1e-4f);
    ws[(size_t)bz * SLAB + OFF_VALID + p] = (msum == 0.0f) ? 1.0f : 0.0f;
}

__device__ __forceinline__ int halo_idx(int k) {
    if (k < 34) return k;
    if (k < 68) return 1122 + (k - 34);
    if (k < 100) return 34 * (k - 100 + 33);
    return 34 * (k - 132 + 33) + 33;
}

// ---- 128x128-tile BK=64 MFMA GEMM core (depth-2 counted vmcnt) ----
template<int KTOT>
__device__ __forceinline__ void gemm_core(const __bf16* __restrict__ Ab,
                                          const __bf16* __restrict__ Bb,
                                          int lda, int ldb, int m0, int n0,
                                          __bf16* As, __bf16* Bs,
                                          f32x4 acc[4][4]) {
    int t = threadIdx.x;
    int lane = t & 63, w = t >> 6;
    int rsub = lane >> 3;
    int g8   = ((lane & 7) ^ (rsub & 7)) * 8;
    int lm = lane & 15, kgf = lane >> 4;
    int wm = (w & 1) * 64, wn = (w >> 1) * 64;

#define ISSUE(kt, buf) do {                                                   \
    int k0_ = (kt) * 64;                                                      \
    _Pragma("unroll")                                                         \
    for (int ci = 0; ci < 4; ci++) {                                          \
        int rb = ci * 32 + w * 8;                                             \
        int r  = rb + rsub;                                                   \
        GLDS(Ab + (size_t)(m0 + r) * lda + k0_ + g8, &As[(buf) + rb * 64]);   \
        GLDS(Bb + (size_t)(n0 + r) * ldb + k0_ + g8, &Bs[(buf) + rb * 64]);   \
    } } while (0)

#define COMPUTE(curoff) do {                                                  \
    _Pragma("unroll")                                                         \
    for (int s2 = 0; s2 < 2; s2++) {                                          \
        bf16x8 af[4], bfr[4];                                                 \
        _Pragma("unroll")                                                     \
        for (int i = 0; i < 4; i++)                                           \
            af[i] = *(const bf16x8*)&As[(curoff) + (wm + i * 16 + lm) * 64 +  \
                                        (((s2 * 4 + kgf) ^ (lm & 7)) * 8)];   \
        _Pragma("unroll")                                                     \
        for (int j = 0; j < 4; j++)                                           \
            bfr[j] = *(const bf16x8*)&Bs[(curoff) + (wn + j * 16 + lm) * 64 + \
                                         (((s2 * 4 + kgf) ^ (lm & 7)) * 8)];  \
        _Pragma("unroll")                                                     \
        for (int i = 0; i < 4; i++)                                           \
            _Pragma("unroll")                                                 \
            for (int j = 0; j < 4; j++)                                       \
                acc[i][j] = __builtin_amdgcn_mfma_f32_16x16x32_bf16(          \
                    af[i], bfr[j], acc[i][j], 0, 0, 0);                       \
    } } while (0)

    const int NIT = KTOT / 64;

    ISSUE(0, 0);
    ISSUE(1, 8192);

#pragma unroll 2
    for (int it = 0; it < NIT - 2; it++) {
        int cur = (it & 1) * 8192;
        asm volatile("s_waitcnt vmcnt(8)" ::: "memory");
        __builtin_amdgcn_sched_barrier(0);
        __builtin_amdgcn_s_barrier();
        COMPUTE(cur);
        __builtin_amdgcn_s_barrier();
        ISSUE(it + 2, cur);
    }
    asm volatile("s_waitcnt vmcnt(8)" ::: "memory");
    __builtin_amdgcn_sched_barrier(0);
    __builtin_amdgcn_s_barrier();
    COMPUTE(((NIT - 2) & 1) * 8192);
    __builtin_amdgcn_s_barrier();
    asm volatile("s_waitcnt vmcnt(0)" ::: "memory");
    __builtin_amdgcn_sched_barrier(0);
    __builtin_amdgcn_s_barrier();
    COMPUTE(((NIT - 1) & 1) * 8192);

#undef ISSUE
#undef COMPUTE
}

// ---- T GEMM (bf16x3 == fp32), padded-4D epilogue + folded halo-zero ----
__global__ __launch_bounds__(256) void k_gemm_T_mfma(float* __restrict__ ws, int swz) {
    int bz, m0, n0;
    if (swz) {
        bz = blockIdx.x + 8 * (blockIdx.z & 1);
        m0 = blockIdx.y * 128;
        n0 = (blockIdx.z >> 1) * 128;
    } else {
        bz = blockIdx.z; m0 = blockIdx.y * 128; n0 = blockIdx.x * 128;
    }
    const __bf16* Ab = (const __bf16*)(ws + (size_t)bz * SLAB + OFF_POOL);
    const __bf16* Bb = Ab + 393216;
    float* Tp = ws + (size_t)bz * SLAB + OFF_TP;
    __shared__ __align__(16) __bf16 As[2 * 128 * 64];
    __shared__ __align__(16) __bf16 Bs[2 * 128 * 64];
    f32x4 acc[4][4];
#pragma unroll
    for (int i = 0; i < 4; i++)
#pragma unroll
        for (int j = 0; j < 4; j++) acc[i][j] = (f32x4)0.0f;
    gemm_core<KC>(Ab, Bb, KC, KC, m0, n0, As, Bs, acc);
    int lane = threadIdx.x & 63, w = threadIdx.x >> 6;
    int lm = lane & 15, kgf = lane >> 4;
    int wm = (w & 1) * 64, wn = (w >> 1) * 64;
#pragma unroll
    for (int i = 0; i < 4; i++) {
#pragma unroll
        for (int r = 0; r < 4; r++) {
            int m = m0 + wm + i * 16 + kgf * 4 + r;
            float* dst = Tp + (size_t)(((m >> 5) + 1) * 34 + (m & 31) + 1) * TPD;
#pragma unroll
            for (int j = 0; j < 4; j++) {
                int v = n0 + wn + j * 16 + lm;
                dst[((v >> 5) + 1) * 34 + (v & 31) + 1] = acc[i][j][r];
            }
        }
    }
    // folded zerohalo: the 64 blocks of this batch cooperatively zero the
    // NHALO halo cells (disjoint from interior stores; s12 runs next launch)
    int cb = (m0 >> 7) * 8 + (n0 >> 7);            // [0,64) per batch
    for (int h = cb * 256 + (int)threadIdx.x; h < NHALO; h += 64 * 256) {
        if (h < NH1) {
            int R = halo_idx(h / TPD);
            Tp[(size_t)R * TPD + (h % TPD)] = 0.f;
        } else {
            int t2 = h - NH1;
            int ir = t2 / NHROW;
            int R  = 34 * (1 + (ir >> 5)) + 1 + (ir & 31);
            int C  = halo_idx(t2 % NHROW);
            Tp[(size_t)R * TPD + C] = 0.f;
        }
    }
}

// ---- W GEMM, 288x256 tile, 512 threads / 8 waves, grid = 256 = ONE round
// R10's spill diagnosed: launch_bounds(512,2) caps the unified VGPR+AGPR
// budget at 256/wave while acc[9][4](144 AGPR)+operands+addr needs ~200+;
// compiler split 128V+144A > 256 -> scratch (WRITE 120MB, FETCH 237MB).
// Fix: (512,1) doubles the allocator budget (m08: no spill to ~450);
// LDS 136KiB already forces 1 block/CU so occupancy is unchanged.
// Inner loop restructured for minimal live range: bfr[4] once per ks,
// then per-mi {1 af load -> 4 MFMAs}.
__global__ __launch_bounds__(512, 1) void k_gemm_W288(float* __restrict__ ws) {
    int d = blockIdx.x;                 // 256 blocks, linear decode
    int bz  = d >> 4;
    int t16 = d & 15;
    int m0 = (t16 >> 2) * 288;          // 4 M-tiles exact
    int n0 = (t16 & 3) * 256;
    const __bf16* Ab = (const __bf16*)(ws + (size_t)bz * SLAB + OFF_POOL);
    const __bf16* Bb = (const __bf16*)(ws + (size_t)bz * SLAB + OFF_SCORET);
    __bf16* Wb = (__bf16*)(ws + (size_t)bz * SLAB + OFF_W);
    __shared__ __align__(16) __bf16 As[2 * 288 * 64];   // 72 KiB
    __shared__ __align__(16) __bf16 Bs[2 * 256 * 64];   // 64 KiB

    int t = threadIdx.x;
    int lane = t & 63, w = t >> 6;
    int rsub = lane >> 3;
    int g8   = ((lane & 7) ^ (rsub & 7)) * 8;
    int lm = lane & 15, kgf = lane >> 4;
    int wr = (w >> 2) * 144;            // wave M-offset (0/144)
    int wc = (w & 3) * 64;              // wave N-offset (0/64/128/192)

    f32x4 acc[9][4];
#pragma unroll
    for (int i = 0; i < 9; i++)
#pragma unroll
        for (int j = 0; j < 4; j++) acc[i][j] = (f32x4)0.0f;

    // A: 288 rows = 4 full wave-rounds (256) + rows 256-287 by waves 0-3.
    // B: 256 rows = 4 full wave-rounds. 9 (or 10) GLDS per thread.
#define WSTAGE(nbA, nbB, k1_) do {                                            \
    _Pragma("unroll")                                                         \
    for (int ci = 0; ci < 4; ci++) {                                          \
        int rb = ci * 64 + w * 8;                                             \
        GLDS(Ab + (size_t)(m0 + rb + rsub) * LL + (k1_) + g8,                 \
             &As[(nbA) + rb * 64]);                                           \
    }                                                                         \
    if (w < 4) {                                                              \
        int rb = 256 + w * 8;                                                 \
        GLDS(Ab + (size_t)(m0 + rb + rsub) * LL + (k1_) + g8,                 \
             &As[(nbA) + rb * 64]);                                           \
    }                                                                         \
    _Pragma("unroll")                                                         \
    for (int ci = 0; ci < 4; ci++) {                                          \
        int rb = ci * 64 + w * 8;                                             \
        GLDS(Bb + (size_t)(n0 + rb + rsub) * LL + (k1_) + g8,                 \
             &Bs[(nbB) + rb * 64]);                                           \
    } } while (0)

    WSTAGE(0, 0, 0);
    asm volatile("s_waitcnt vmcnt(0)" ::: "memory");
    __builtin_amdgcn_sched_barrier(0);
    __builtin_amdgcn_s_barrier();

#pragma unroll 2
    for (int kt = 0; kt < 16; kt++) {
        int boA = (kt & 1) * 18432, boB = (kt & 1) * 16384;
        int nbA = boA ^ 18432, nbB = boB ^ 16384;
        if (kt < 15) WSTAGE(nbA, nbB, (kt + 1) * 64);
#pragma unroll
        for (int ks = 0; ks < 2; ks++) {
            bf16x8 bfr[4];
            int ko = ((ks * 4 + kgf) ^ (lm & 7)) * 8;
#pragma unroll
            for (int nj = 0; nj < 4; nj++)
                bfr[nj] = *(const bf16x8*)&Bs[boB + (wc + nj * 16 + lm) * 64 + ko];
            __builtin_amdgcn_s_setprio(1);
#pragma unroll
            for (int mi = 0; mi < 9; mi++) {
                bf16x8 af = *(const bf16x8*)&As[boA + (wr + mi * 16 + lm) * 64 + ko];
#pragma unroll
                for (int nj = 0; nj < 4; nj++)
                    acc[mi][nj] = __builtin_amdgcn_mfma_f32_16x16x32_bf16(
                        af, bfr[nj], acc[mi][nj], 0, 0, 0);
            }
            __builtin_amdgcn_s_setprio(0);
        }
        if (kt < 15) {
            asm volatile("s_waitcnt vmcnt(0)" ::: "memory");
            __builtin_amdgcn_sched_barrier(0);
            __builtin_amdgcn_s_barrier();
        }
    }

#undef WSTAGE

#pragma unroll
    for (int mf = 0; mf < 9; mf++) {
#pragma unroll
        for (int r = 0; r < 4; r++) {
            int m = m0 + wr + mf * 16 + kgf * 4 + r;   // always < 1152
            __bf16* dst = Wb + (size_t)m * LL + n0 + wc + lm;
#pragma unroll
            for (int nj = 0; nj < 4; nj++)
                dst[nj * 16] = (__bf16)acc[mf][nj][r];
        }
    }
}

// ---- W[m,q] GEMM 128-tile fallback (Gc<16 path) ----
__global__ __launch_bounds__(256) void k_gemm_W_mfma(float* __restrict__ ws, int swz) {
    int bz, m0, n0;
    if (swz) {
        bz = blockIdx.x + 8 * (blockIdx.z & 1);
        m0 = blockIdx.y * 128;
        n0 = (blockIdx.z >> 1) * 128;
    } else {
        bz = blockIdx.z; m0 = blockIdx.y * 128; n0 = blockIdx.x * 128;
    }
    const __bf16* Ab = (const __bf16*)(ws + (size_t)bz * SLAB + OFF_POOL);
    const __bf16* Bb = (const __bf16*)(ws + (size_t)bz * SLAB + OFF_SCORET);
    __bf16* Wb = (__bf16*)(ws + (size_t)bz * SLAB + OFF_W);
    __shared__ __align__(16) __bf16 As[2 * 128 * 64];
    __shared__ __align__(16) __bf16 Bs[2 * 128 * 64];
    f32x4 acc[4][4];
#pragma unroll
    for (int i = 0; i < 4; i++)
#pragma unroll
        for (int j = 0; j < 4; j++) acc[i][j] = (f32x4)0.0f;
    gemm_core<LL>(Ab, Bb, LL, LL, m0, n0, As, Bs, acc);
    int lane = threadIdx.x & 63, w = threadIdx.x >> 6;
    int lm = lane & 15, kgf = lane >> 4;
    int wm = (w & 1) * 64, wn = (w >> 1) * 64;
#pragma unroll
    for (int i = 0; i < 4; i++) {
#pragma unroll
        for (int r = 0; r < 4; r++) {
            int m = m0 + wm + i * 16 + kgf * 4 + r;
            __bf16* dst = Wb + (size_t)m * LL + n0 + wn + lm;
#pragma unroll
            for (int j = 0; j < 4; j++)
                dst[j * 16] = (__bf16)acc[i][j][r];
        }
    }
}

// ---- fused st1+st2 (padded T, 9 unconditional loads per element) ----
__global__ __launch_bounds__(256) void k_s12(float* __restrict__ ws, int aff) {
    int bz, i0;
    if (aff) { int g = blockIdx.x; bz = g & 15; i0 = (g >> 4) * 8; }
    else     { bz = blockIdx.y; i0 = blockIdx.x * 8; }
    const float* Tp = ws + (size_t)bz * SLAB + OFF_TP;
    const float* bn = ws + (size_t)bz * SLAB + OFF_BNORM;
    float* S2 = ws + (size_t)bz * SLAB + OFF_S2;
    __shared__ float Dsh[10][1024];
    int tid = threadIdx.x;
    for (int rl = 0; rl < 10; rl++) {
        int r = i0 - 1 + rl;
        if ((unsigned)r >= 1024u) continue;
        float invr = 1.0f / bn[r];
        size_t rbase = (size_t)(((r >> 5) + 1) * 34 + (r & 31) + 1) * TPD;
#pragma unroll
        for (int so = 0; so < 4; so++) {
            int s = so * 256 + tid;
            const float* cb = Tp + rbase + ((s >> 5) + 1) * 34 + (s & 31) + 1;
            float d = 0.f;
#pragma unroll
            for (int dy = -1; dy <= 1; dy++)
#pragma unroll
                for (int dx = -1; dx <= 1; dx++)
                    d += cb[dy * (34 * TPD + 34) + dx * (TPD + 1)];
            Dsh[rl][s] = d * invr;
        }
    }
    __syncthreads();
#pragma unroll
    for (int il = 0; il < 8; il++) {
        int i = i0 + il;
        float* orow = S2 + (size_t)i * LL;
#pragma unroll
        for (int jo = 0; jo < 4; jo++) {
            int j = jo * 256 + tid;
            float acc = 0.f;
#pragma unroll
            for (int k1 = -1; k1 <= 1; k1++) {
                int r = i + k1, s = j + k1;
                if ((unsigned)r < 1024u && (unsigned)s < 1024u)
                    acc += Dsh[il + 1 + k1][s];
            }
            orow[j] = acc;
        }
    }
}

// ---- second diag_fuse (sigma-space) fused with transpose: S3T[q][p] ----
__global__ __launch_bounds__(256) void k_st3t(float* __restrict__ ws, int aff) {
    int bz, p0, q0;
    if (aff) {
        int g = blockIdx.x; bz = g & 15;
        int tile = g >> 4; p0 = (tile >> 4) * 64; q0 = (tile & 15) * 64;
    } else {
        bz = blockIdx.z; p0 = blockIdx.y * 64; q0 = blockIdx.x * 64;
    }
    const float* ib = ws + (size_t)bz * SLAB + OFF_S2;
    float* ob = ws + (size_t)bz * SLAB + OFF_S3T;
    __shared__ float tile[64][65];
    int t = threadIdx.x;
#pragma unroll
    for (int it = 0; it < 16; it++) {
        int e = it * 256 + t;
        int pl = e >> 6, ql = e & 63;
        int p = p0 + pl, q = q0 + ql;
        int sp = ((p & 31) << 5) | (p >> 5);
        int sq = ((q & 31) << 5) | (q >> 5);
        float acc = 0.f;
#pragma unroll
        for (int k = -1; k <= 1; k++) {
            int tp = sp + k, tq = sq + k;
            if ((unsigned)tp < 1024u && (unsigned)tq < 1024u) {
                int row = ((tp & 31) << 5) | (tp >> 5);
                int col = ((tq & 31) << 5) | (tq >> 5);
                acc += ib[(size_t)row * LL + col];
            }
        }
        tile[pl][ql] = acc;
    }
    __syncthreads();
#pragma unroll
    for (int it = 0; it < 16; it++) {
        int e = it * 256 + t;
        int ql = e >> 6, pl = e & 63;
        ob[(size_t)(q0 + ql) * LL + p0 + pl] = tile[pl][ql];
    }
}

// ---- row softmax on S3T, writes bf16 scoreT[q][p] ----
__global__ __launch_bounds__(256) void k_softmax_bf(float* __restrict__ ws, int aff) {
    int bz, q;
    if (aff) {
        int g = blockIdx.x; bz = g & 15;
        q = (g >> 4) * 4 + (threadIdx.x >> 6);
    } else {
        bz = blockIdx.z;
        q = blockIdx.x * 4 + (threadIdx.x >> 6);
    }
    int lane = threadIdx.x & 63;
    const float* row = ws + (size_t)bz * SLAB + OFF_S3T + (size_t)q * LL;
    const float* vb  = ws + (size_t)bz * SLAB + OFF_VALID;
    __bf16* orow = (__bf16*)(ws + (size_t)bz * SLAB + OFF_SCORET) + (size_t)q * LL;

    float4 v[4], vl[4];
#pragma unroll
    for (int i = 0; i < 4; i++) {
        int p = lane * 4 + i * 256;
        float4 s = *(const float4*)(row + p);
        float4 m = *(const float4*)(vb + p);
        v[i] = {s.x * m.x, s.y * m.y, s.z * m.z, s.w * m.w};
        vl[i] = m;
    }
    float mx = -1e30f;
#pragma unroll
    for (int i = 0; i < 4; i++)
        mx = fmaxf(mx, fmaxf(fmaxf(v[i].x, v[i].y), fmaxf(v[i].z, v[i].w)));
#pragma unroll
    for (int k = 1; k < 64; k <<= 1)
        mx = fmaxf(mx, __shfl_xor(mx, k, 64));
    float sum = 0.f;
    float4 e[4];
#pragma unroll
    for (int i = 0; i < 4; i++) {
        e[i].x = __expf(10.f * (v[i].x - mx));
        e[i].y = __expf(10.f * (v[i].y - mx));
        e[i].z = __expf(10.f * (v[i].z - mx));
        e[i].w = __expf(10.f * (v[i].w - mx));
        sum += e[i].x + e[i].y + e[i].z + e[i].w;
    }
#pragma unroll
    for (int k = 1; k < 64; k <<= 1)
        sum += __shfl_xor(sum, k, 64);
    float inv = 1.0f / sum;
#pragma unroll
    for (int i = 0; i < 4; i++) {
        bf16x4 o;
        o[0] = (__bf16)(e[i].x * inv * vl[i].x);
        o[1] = (__bf16)(e[i].y * inv * vl[i].y);
        o[2] = (__bf16)(e[i].z * inv * vl[i].z);
        o[3] = (__bf16)(e[i].w * inv * vl[i].w);
        *(bf16x4*)(orow + lane * 4 + i * 256) = o;
    }
}

// ---- coalesced makeA: block per (channel, batch); LDS image tile ----
__global__ __launch_bounds__(256) void k_makeA(const float* __restrict__ b_o,
                                               float* __restrict__ ws,
                                               int b0, int aff) {
    int c, bz;
    if (aff) { int g = blockIdx.x; bz = g & 15; c = g >> 4; }
    else     { c = blockIdx.x; bz = blockIdx.y; }
    int gb = b0 + bz;
    __shared__ float img[64][65];
    int t = threadIdx.x;
    const float4* src = (const float4*)(b_o + (size_t)(gb * CC + c) * HH * WWI);
#pragma unroll
    for (int it = 0; it < 4; it++) {
        int idx = it * 256 + t;
        float4 v = src[idx];
        int row = idx >> 4, col4 = (idx & 15) * 4;
        img[row][col4] = v.x; img[row][col4 + 1] = v.y;
        img[row][col4 + 2] = v.z; img[row][col4 + 3] = v.w;
    }
    __syncthreads();
    __bf16* Ab = (__bf16*)(ws + (size_t)bz * SLAB + OFF_POOL) + (size_t)c * 9 * LL;
    int py = t >> 3, px4 = (t & 7) * 4;
#pragma unroll
    for (int jy = 0; jy < 3; jy++) {
        int row = 2 * py + jy - 1;
        bool rok = (unsigned)row < 64u;
#pragma unroll
        for (int jx = 0; jx < 3; jx++) {
            bf16x4 o;
#pragma unroll
            for (int e = 0; e < 4; e++) {
                int col = 2 * (px4 + e) + jx - 1;
                float v = (rok && (unsigned)col < 64u) ? img[rok ? row : 0][(unsigned)col < 64u ? col : 0] : 0.f;
                o[e] = (__bf16)v;
            }
            *(bf16x4*)(Ab + (size_t)(jy * 3 + jx) * LL + t * 4) = o;
        }
    }
}

// ---- gather: out[c,oy,ox] = 0.25 * sum of <=4 bf16 W taps ----
__global__ __launch_bounds__(256) void k_gather(const float* __restrict__ ws,
                                                float* __restrict__ outp,
                                                int b0, int aff) {
    int t;
    if (aff) {
        int g = blockIdx.x;
        int bz_ = g & 15;
        t = (bz_ << 19) + (g >> 4) * 256 + threadIdx.x;
    } else {
        t = blockIdx.x * 256 + threadIdx.x;
    }
    int ox = t & 63, oy = (t >> 6) & 63, c = (t >> 12) & 127, bz = t >> 19;
    const __bf16* Wb = (const __bf16*)(ws + (size_t)bz * SLAB + OFF_W);
    int qyA = (oy + 1) >> 1;
    int jyA = (oy & 1) ? 0 : 1;
    int vA  = (qyA < 32);
    int qyB = (oy - 1) >> 1;
    int vB  = (oy & 1);
    int qxA = (ox + 1) >> 1;
    int jxA = (ox & 1) ? 0 : 1;
    int uA  = (qxA < 32);
    int qxB = (ox - 1) >> 1;
    int uB  = (ox & 1);
    const __bf16* base = Wb + (size_t)c * 9 * LL;
    float s = 0.f;
    if (vA && uA) s += (float)base[(size_t)(jyA * 3 + jxA) * LL + qyA * 32 + qxA];
    if (vA && uB) s += (float)base[(size_t)(jyA * 3 + 2)   * LL + qyA * 32 + qxB];
    if (vB && uA) s += (float)base[(size_t)(2 * 3 + jxA)   * LL + qyB * 32 + qxA];
    if (vB && uB) s += (float)base[(size_t)(2 * 3 + 2)     * LL + qyB * 32 + qxB];
    outp[((size_t)((b0 + bz) * CC + c) * HH + oy) * WWI + ox] = 0.25f * s;
}

extern "C" void kernel_launch(void* const* d_in, const int* in_sizes, int n_in,
                              void* d_out, int out_size, void* d_ws, size_t ws_size,
                              hipStream_t stream) {
    (void)in_sizes; (void)n_in; (void)out_size;
    const float* f_o  = (const float*)d_in[0];
    const float* b_o  = (const float*)d_in[1];
    const float* mask = (const float*)d_in[2];
    float* out = (float*)d_out;

    int G = (int)(ws_size / (SLAB * sizeof(float)));   // ~11.9 MB per batch slab
    if (G < 1) G = 1;
    if (G > NB) G = NB;
    float* ws = (float*)d_ws;

    for (int b0 = 0; b0 < NB; b0 += G) {
        int Gc = NB - b0 < G ? NB - b0 : G;
        if (Gc == NB) {
            // XCD-affinity path for the chain; W = 288-tile, 1 round
            k_prep<<<dim3(512), 256, 0, stream>>>(f_o, b_o, ws, 0, 1);
            k_bnorm_valid<<<dim3(64), 256, 0, stream>>>(ws, mask, 0, 1);
            k_gemm_T_mfma<<<dim3(8, 8, 16), 256, 0, stream>>>(ws, 1);
            k_s12<<<dim3(2048), 256, 0, stream>>>(ws, 1);
            k_st3t<<<dim3(4096), 256, 0, stream>>>(ws, 1);
            k_softmax_bf<<<dim3(4096), 256, 0, stream>>>(ws, 1);
            k_makeA<<<dim3(2048), 256, 0, stream>>>(b_o, ws, 0, 1);
            k_gemm_W288<<<dim3(256), 512, 0, stream>>>(ws);
            k_gather<<<dim3(32768), 256, 0, stream>>>(ws, out, 0, 1);
        } else {
            k_prep<<<dim3(32, Gc), 256, 0, stream>>>(f_o, b_o, ws, b0, 0);
            k_bnorm_valid<<<dim3(Gc * 4), 256, 0, stream>>>(ws, mask, b0, 0);
            k_gemm_T_mfma<<<dim3(8, 8, Gc), 256, 0, stream>>>(ws, 0);
            k_s12<<<dim3(128, Gc), 256, 0, stream>>>(ws, 0);
            k_st3t<<<dim3(16, 16, Gc), 256, 0, stream>>>(ws, 0);
            k_softmax_bf<<<dim3(256, 1, Gc), 256, 0, stream>>>(ws, 0);
            k_makeA<<<dim3(CC, Gc), 256, 0, stream>>>(b_o, ws, b0, 0);
            k_gemm_W_mfma<<<dim3(8, 9, Gc), 256, 0, stream>>>(ws, 0);
            k_gather<<<dim3(Gc * 2048), 256, 0, stream>>>(ws, out, b0, 0);
        }
    }
}

// Round 12
// 348.993 us; speedup vs baseline: 1.1302x; 1.0880x over previous
//
#include <hip/hip_runtime.h>
#include <cmath>

#define CC 128
#define HH 64
#define WWI 64
#define LL 1024
#define NB 16
#define MM 1152          // 128 channels * 9 taps
#define KC 384           // concat K for bf16x3 T-GEMM
#define TPD 1156         // 34*34 padded dim

// per-batch slab layout (floats):
#define SLAB      2977808ul
#define OFF_TP    0
#define OFF_S3T   0
#define OFF_W     0
#define OFF_S2    1336336
#define OFF_SCORET 1336336
#define OFF_POOL  2384912
#define OFF_N2    2974736
#define OFF_BNORM 2975760
#define OFF_VALID 2976784

// halo geometry (zeroing folded into k_gemm_T epilogue)
#define NHROW 132
#define NH1 (NHROW * TPD)
#define NHALO (NH1 + 1024 * NHROW)

typedef __bf16 bf16x8 __attribute__((ext_vector_type(8)));
typedef __bf16 bf16x4 __attribute__((ext_vector_type(4)));
typedef float f32x4 __attribute__((ext_vector_type(4)));

#define GLDS(g, l) __builtin_amdgcn_global_load_lds( \
    (const __attribute__((address_space(1))) unsigned int*)(const void*)(g), \
    (__attribute__((address_space(3))) unsigned int*)(void*)(l), 16, 0, 0)

// ---- downsample + transpose (LDS tile) + bf16 hi/lo concat + fused n2 ----
__global__ __launch_bounds__(256) void k_prep(const float* __restrict__ f_o,
                                              const float* __restrict__ b_o,
                                              float* __restrict__ ws,
                                              int b0, int aff) {
    int bz, uy;
    if (aff) { int g = blockIdx.x; bz = g & 15; uy = g >> 4; }
    else     { bz = blockIdx.y; uy = blockIdx.x; }
    int gb = b0 + bz;
    __shared__ float lf[128 * 33];
    __shared__ float lb[128 * 33];
    __shared__ float red[8 * 32];
    int tid = threadIdx.x;
    int ux = tid & 31, co = tid >> 5;
    size_t pix = (size_t)(2 * uy) * WWI + 2 * ux;
    const float* fbp = f_o + (size_t)gb * CC * HH * WWI + pix;
    const float* bbp = b_o + (size_t)gb * CC * HH * WWI + pix;
#pragma unroll
    for (int pass = 0; pass < 16; pass++) {
        int c = pass * 8 + co;
        lf[c * 33 + ux] = fbp[(size_t)c * HH * WWI];
        lb[c * 33 + ux] = bbp[(size_t)c * HH * WWI];
    }
    __syncthreads();
    int ux2 = tid >> 3, cg = (tid & 7) * 16;
    int u = uy * 32 + ux2;
    __bf16* bcat = (__bf16*)(ws + (size_t)bz * SLAB + OFF_POOL) + (size_t)u * KC;
    __bf16* fcat = bcat + 393216;
    float s2 = 0.f;
#pragma unroll
    for (int k = 0; k < 16; k++) {
        int c = cg + k;
        float fv = lf[c * 33 + ux2];
        float bv = lb[c * 33 + ux2];
        __bf16 fhi = (__bf16)fv; __bf16 flo = (__bf16)(fv - (float)fhi);
        __bf16 bhi = (__bf16)bv; __bf16 blo = (__bf16)(bv - (float)bhi);
        bcat[c] = bhi; bcat[128 + c] = bhi; bcat[256 + c] = blo;
        fcat[c] = fhi; fcat[128 + c] = flo; fcat[256 + c] = fhi;
        s2 += bv * bv;
    }
    red[(tid & 7) * 32 + ux2] = s2;
    __syncthreads();
    if (tid < 32) {
        float s = 0.f;
#pragma unroll
        for (int k = 0; k < 8; k++) s += red[k * 32 + tid];
        ws[(size_t)bz * SLAB + OFF_N2 + uy * 32 + tid] = s;
    }
}

__global__ __launch_bounds__(256) void k_bnorm_valid(float* __restrict__ ws,
                                                     const float* __restrict__ mask,
                                                     int b0, int aff) {
    int g = blockIdx.x;
    int bz, pc;
    if (aff) { bz = g & 15; pc = g >> 4; }
    else     { bz = g >> 2; pc = g & 3; }
    int p = pc * 256 + threadIdx.x;
    int gb = b0 + bz;
    int py = p >> 5, px = p & 31;
    const float* mb = mask + (size_t)gb * HH * WWI;
    const float* n2 = ws + (size_t)bz * SLAB + OFF_N2;
    float s = 0.f, msum = 0.f;
#pragma unroll
    for (int dy = -1; dy <= 1; dy++) {
#pragma unroll
        for (int dx = -1; dx <= 1; dx++) {
            int py2 = py + dy, px2 = px + dx;
            if ((unsigned)py2 < 32u && (unsigned)px2 < 32u) {
                s    += n2[(py2 << 5) | px2];
                msum += mb[(2 * py2) * WWI + 2 * px2];
            }
        }
    }
    ws[(size_t)bz * SLAB + OFF_BNORM + p] = fmaxf(sqrtf(s), 1e-4f);
    ws[(size_t)bz * SLAB + OFF_VALID + p] = (msum == 0.0f) ? 1.0f : 0.0f;
}

__device__ __forceinline__ int halo_idx(int k) {
    if (k < 34) return k;
    if (k < 68) return 1122 + (k - 34);
    if (k < 100) return 34 * (k - 100 + 33);
    return 34 * (k - 132 + 33) + 33;
}

// ---- 128x128-tile BK=64 MFMA GEMM core (depth-2 counted vmcnt) ----
template<int KTOT>
__device__ __forceinline__ void gemm_core(const __bf16* __restrict__ Ab,
                                          const __bf16* __restrict__ Bb,
                                          int lda, int ldb, int m0, int n0,
                                          __bf16* As, __bf16* Bs,
                                          f32x4 acc[4][4]) {
    int t = threadIdx.x;
    int lane = t & 63, w = t >> 6;
    int rsub = lane >> 3;
    int g8   = ((lane & 7) ^ (rsub & 7)) * 8;
    int lm = lane & 15, kgf = lane >> 4;
    int wm = (w & 1) * 64, wn = (w >> 1) * 64;

#define ISSUE(kt, buf) do {                                                   \
    int k0_ = (kt) * 64;                                                      \
    _Pragma("unroll")                                                         \
    for (int ci = 0; ci < 4; ci++) {                                          \
        int rb = ci * 32 + w * 8;                                             \
        int r  = rb + rsub;                                                   \
        GLDS(Ab + (size_t)(m0 + r) * lda + k0_ + g8, &As[(buf) + rb * 64]);   \
        GLDS(Bb + (size_t)(n0 + r) * ldb + k0_ + g8, &Bs[(buf) + rb * 64]);   \
    } } while (0)

#define COMPUTE(curoff) do {                                                  \
    _Pragma("unroll")                                                         \
    for (int s2 = 0; s2 < 2; s2++) {                                          \
        bf16x8 af[4], bfr[4];                                                 \
        _Pragma("unroll")                                                     \
        for (int i = 0; i < 4; i++)                                           \
            af[i] = *(const bf16x8*)&As[(curoff) + (wm + i * 16 + lm) * 64 +  \
                                        (((s2 * 4 + kgf) ^ (lm & 7)) * 8)];   \
        _Pragma("unroll")                                                     \
        for (int j = 0; j < 4; j++)                                           \
            bfr[j] = *(const bf16x8*)&Bs[(curoff) + (wn + j * 16 + lm) * 64 + \
                                         (((s2 * 4 + kgf) ^ (lm & 7)) * 8)];  \
        _Pragma("unroll")                                                     \
        for (int i = 0; i < 4; i++)                                           \
            _Pragma("unroll")                                                 \
            for (int j = 0; j < 4; j++)                                       \
                acc[i][j] = __builtin_amdgcn_mfma_f32_16x16x32_bf16(          \
                    af[i], bfr[j], acc[i][j], 0, 0, 0);                       \
    } } while (0)

    const int NIT = KTOT / 64;

    ISSUE(0, 0);
    ISSUE(1, 8192);

#pragma unroll 2
    for (int it = 0; it < NIT - 2; it++) {
        int cur = (it & 1) * 8192;
        asm volatile("s_waitcnt vmcnt(8)" ::: "memory");
        __builtin_amdgcn_sched_barrier(0);
        __builtin_amdgcn_s_barrier();
        COMPUTE(cur);
        __builtin_amdgcn_s_barrier();
        ISSUE(it + 2, cur);
    }
    asm volatile("s_waitcnt vmcnt(8)" ::: "memory");
    __builtin_amdgcn_sched_barrier(0);
    __builtin_amdgcn_s_barrier();
    COMPUTE(((NIT - 2) & 1) * 8192);
    __builtin_amdgcn_s_barrier();
    asm volatile("s_waitcnt vmcnt(0)" ::: "memory");
    __builtin_amdgcn_sched_barrier(0);
    __builtin_amdgcn_s_barrier();
    COMPUTE(((NIT - 1) & 1) * 8192);

#undef ISSUE
#undef COMPUTE
}

// ---- T GEMM (bf16x3 == fp32), padded-4D epilogue + folded halo-zero ----
__global__ __launch_bounds__(256) void k_gemm_T_mfma(float* __restrict__ ws, int swz) {
    int bz, m0, n0;
    if (swz) {
        bz = blockIdx.x + 8 * (blockIdx.z & 1);
        m0 = blockIdx.y * 128;
        n0 = (blockIdx.z >> 1) * 128;
    } else {
        bz = blockIdx.z; m0 = blockIdx.y * 128; n0 = blockIdx.x * 128;
    }
    const __bf16* Ab = (const __bf16*)(ws + (size_t)bz * SLAB + OFF_POOL);
    const __bf16* Bb = Ab + 393216;
    float* Tp = ws + (size_t)bz * SLAB + OFF_TP;
    __shared__ __align__(16) __bf16 As[2 * 128 * 64];
    __shared__ __align__(16) __bf16 Bs[2 * 128 * 64];
    f32x4 acc[4][4];
#pragma unroll
    for (int i = 0; i < 4; i++)
#pragma unroll
        for (int j = 0; j < 4; j++) acc[i][j] = (f32x4)0.0f;
    gemm_core<KC>(Ab, Bb, KC, KC, m0, n0, As, Bs, acc);
    int lane = threadIdx.x & 63, w = threadIdx.x >> 6;
    int lm = lane & 15, kgf = lane >> 4;
    int wm = (w & 1) * 64, wn = (w >> 1) * 64;
#pragma unroll
    for (int i = 0; i < 4; i++) {
#pragma unroll
        for (int r = 0; r < 4; r++) {
            int m = m0 + wm + i * 16 + kgf * 4 + r;
            float* dst = Tp + (size_t)(((m >> 5) + 1) * 34 + (m & 31) + 1) * TPD;
#pragma unroll
            for (int j = 0; j < 4; j++) {
                int v = n0 + wn + j * 16 + lm;
                dst[((v >> 5) + 1) * 34 + (v & 31) + 1] = acc[i][j][r];
            }
        }
    }
    // folded zerohalo: the 64 blocks of this batch cooperatively zero the
    // NHALO halo cells (disjoint from interior stores; s12 runs next launch)
    int cb = (m0 >> 7) * 8 + (n0 >> 7);            // [0,64) per batch
    for (int h = cb * 256 + (int)threadIdx.x; h < NHALO; h += 64 * 256) {
        if (h < NH1) {
            int R = halo_idx(h / TPD);
            Tp[(size_t)R * TPD + (h % TPD)] = 0.f;
        } else {
            int t2 = h - NH1;
            int ir = t2 / NHROW;
            int R  = 34 * (1 + (ir >> 5)) + 1 + (ir & 31);
            int C  = halo_idx(t2 % NHROW);
            Tp[(size_t)R * TPD + C] = 0.f;
        }
    }
}

// ---- W GEMM, 192x256 tile, 512 threads / 8 waves (measured best: 61.8us)
// Issue-early staging: all 7 GLDS for K-tile kt+1 issued at the TOP of
// K-tile kt; boundary vmcnt(0)+barrier once per K-tile. Spread decode.
// PARKED: five alternative schedules (depth-2 vmcnt(8), 4-subphase,
// barrier-pair phases, XCD affinity, 256/288 tiles) all measured >= this.
__global__ __launch_bounds__(512, 2) void k_gemm_W192(float* __restrict__ ws) {
    int d = blockIdx.x;                 // 384 blocks
    int logical = (d & 7) * 48 + (d >> 3);
    int bz  = logical / 24;
    int t24 = logical % 24;
    int m0 = (t24 >> 2) * 192;          // 6 M-tiles exact
    int n0 = (t24 & 3) * 256;
    const __bf16* Ab = (const __bf16*)(ws + (size_t)bz * SLAB + OFF_POOL);
    const __bf16* Bb = (const __bf16*)(ws + (size_t)bz * SLAB + OFF_SCORET);
    __bf16* Wb = (__bf16*)(ws + (size_t)bz * SLAB + OFF_W);
    __shared__ __align__(16) __bf16 As[2 * 192 * 64];   // 48 KiB
    __shared__ __align__(16) __bf16 Bs[2 * 256 * 64];   // 64 KiB

    int t = threadIdx.x;
    int lane = t & 63, w = t >> 6;
    int rsub = lane >> 3;
    int g8   = ((lane & 7) ^ (rsub & 7)) * 8;
    int lm = lane & 15, kgf = lane >> 4;
    int wr = (w >> 2) * 96;             // wave M-offset (0/96)
    int wc = (w & 3) * 64;              // wave N-offset (0/64/128/192)

    f32x4 acc[6][4];
#pragma unroll
    for (int i = 0; i < 6; i++)
#pragma unroll
        for (int j = 0; j < 4; j++) acc[i][j] = (f32x4)0.0f;

#define WSTAGE(nbA, nbB, k1_) do {                                            \
    _Pragma("unroll")                                                         \
    for (int ci = 0; ci < 3; ci++) {                                          \
        int rb = ci * 64 + w * 8;                                             \
        GLDS(Ab + (size_t)(m0 + rb + rsub) * LL + (k1_) + g8,                 \
             &As[(nbA) + rb * 64]);                                           \
    }                                                                         \
    _Pragma("unroll")                                                         \
    for (int ci = 0; ci < 4; ci++) {                                          \
        int rb = ci * 64 + w * 8;                                             \
        GLDS(Bb + (size_t)(n0 + rb + rsub) * LL + (k1_) + g8,                 \
             &Bs[(nbB) + rb * 64]);                                           \
    } } while (0)

#define RD_A(mh, boA) do {                                                    \
    _Pragma("unroll")                                                         \
    for (int mi = 0; mi < 3; mi++)                                            \
        _Pragma("unroll")                                                     \
        for (int ks = 0; ks < 2; ks++)                                        \
            af[mi][ks] = *(const bf16x8*)&As[(boA) +                          \
                (wr + (mh) * 48 + mi * 16 + lm) * 64 +                        \
                (((ks * 4 + kgf) ^ (lm & 7)) * 8)];                           \
    } while (0)

#define RD_B(njlo, boB) do {                                                  \
    _Pragma("unroll")                                                         \
    for (int nj = 0; nj < 2; nj++)                                            \
        _Pragma("unroll")                                                     \
        for (int ks = 0; ks < 2; ks++)                                        \
            bfr[(njlo) + nj][ks] = *(const bf16x8*)&Bs[(boB) +                \
                (wc + ((njlo) + nj) * 16 + lm) * 64 +                         \
                (((ks * 4 + kgf) ^ (lm & 7)) * 8)];                           \
    } while (0)

#define QMFMA(mb, njlo) do {                                                  \
    __builtin_amdgcn_s_setprio(1);                                            \
    _Pragma("unroll")                                                         \
    for (int ks = 0; ks < 2; ks++)                                            \
        _Pragma("unroll")                                                     \
        for (int mi = 0; mi < 3; mi++)                                        \
            _Pragma("unroll")                                                 \
            for (int nj = 0; nj < 2; nj++)                                    \
                acc[(mb) + mi][(njlo) + nj] =                                 \
                    __builtin_amdgcn_mfma_f32_16x16x32_bf16(                  \
                        af[mi][ks], bfr[(njlo) + nj][ks],                     \
                        acc[(mb) + mi][(njlo) + nj], 0, 0, 0);                \
    __builtin_amdgcn_s_setprio(0);                                            \
    } while (0)

    WSTAGE(0, 0, 0);
    asm volatile("s_waitcnt vmcnt(0)" ::: "memory");
    __builtin_amdgcn_sched_barrier(0);
    __builtin_amdgcn_s_barrier();

#pragma unroll 2
    for (int kt = 0; kt < 16; kt++) {
        int boA = (kt & 1) * 12288, boB = (kt & 1) * 16384;
        int nbA = boA ^ 12288, nbB = boB ^ 16384;
        bf16x8 af[3][2], bfr[4][2];
        if (kt < 15) WSTAGE(nbA, nbB, (kt + 1) * 64);
        RD_A(0, boA);
        RD_B(0, boB);
        QMFMA(0, 0);
        RD_B(2, boB);
        QMFMA(0, 2);
        RD_A(1, boA);
        QMFMA(3, 2);
        QMFMA(3, 0);
        if (kt < 15) {
            asm volatile("s_waitcnt vmcnt(0)" ::: "memory");
            __builtin_amdgcn_sched_barrier(0);
            __builtin_amdgcn_s_barrier();
        }
    }

#undef WSTAGE
#undef RD_A
#undef RD_B
#undef QMFMA

#pragma unroll
    for (int mf = 0; mf < 6; mf++) {
#pragma unroll
        for (int r = 0; r < 4; r++) {
            int m = m0 + wr + mf * 16 + kgf * 4 + r;   // always < 1152
            __bf16* dst = Wb + (size_t)m * LL + n0 + wc + lm;
#pragma unroll
            for (int nj = 0; nj < 4; nj++)
                dst[nj * 16] = (__bf16)acc[mf][nj][r];
        }
    }
}

// ---- W[m,q] GEMM 128-tile fallback (Gc<16 path) ----
__global__ __launch_bounds__(256) void k_gemm_W_mfma(float* __restrict__ ws, int swz) {
    int bz, m0, n0;
    if (swz) {
        bz = blockIdx.x + 8 * (blockIdx.z & 1);
        m0 = blockIdx.y * 128;
        n0 = (blockIdx.z >> 1) * 128;
    } else {
        bz = blockIdx.z; m0 = blockIdx.y * 128; n0 = blockIdx.x * 128;
    }
    const __bf16* Ab = (const __bf16*)(ws + (size_t)bz * SLAB + OFF_POOL);
    const __bf16* Bb = (const __bf16*)(ws + (size_t)bz * SLAB + OFF_SCORET);
    __bf16* Wb = (__bf16*)(ws + (size_t)bz * SLAB + OFF_W);
    __shared__ __align__(16) __bf16 As[2 * 128 * 64];
    __shared__ __align__(16) __bf16 Bs[2 * 128 * 64];
    f32x4 acc[4][4];
#pragma unroll
    for (int i = 0; i < 4; i++)
#pragma unroll
        for (int j = 0; j < 4; j++) acc[i][j] = (f32x4)0.0f;
    gemm_core<LL>(Ab, Bb, LL, LL, m0, n0, As, Bs, acc);
    int lane = threadIdx.x & 63, w = threadIdx.x >> 6;
    int lm = lane & 15, kgf = lane >> 4;
    int wm = (w & 1) * 64, wn = (w >> 1) * 64;
#pragma unroll
    for (int i = 0; i < 4; i++) {
#pragma unroll
        for (int r = 0; r < 4; r++) {
            int m = m0 + wm + i * 16 + kgf * 4 + r;
            __bf16* dst = Wb + (size_t)m * LL + n0 + wn + lm;
#pragma unroll
            for (int j = 0; j < 4; j++)
                dst[j * 16] = (__bf16)acc[i][j][r];
        }
    }
}

// ---- fused st1+st2 (padded T, 9 unconditional loads per element) ----
__global__ __launch_bounds__(256) void k_s12(float* __restrict__ ws, int aff) {
    int bz, i0;
    if (aff) { int g = blockIdx.x; bz = g & 15; i0 = (g >> 4) * 8; }
    else     { bz = blockIdx.y; i0 = blockIdx.x * 8; }
    const float* Tp = ws + (size_t)bz * SLAB + OFF_TP;
    const float* bn = ws + (size_t)bz * SLAB + OFF_BNORM;
    float* S2 = ws + (size_t)bz * SLAB + OFF_S2;
    __shared__ float Dsh[10][1024];
    int tid = threadIdx.x;
    for (int rl = 0; rl < 10; rl++) {
        int r = i0 - 1 + rl;
        if ((unsigned)r >= 1024u) continue;
        float invr = 1.0f / bn[r];
        size_t rbase = (size_t)(((r >> 5) + 1) * 34 + (r & 31) + 1) * TPD;
#pragma unroll
        for (int so = 0; so < 4; so++) {
            int s = so * 256 + tid;
            const float* cb = Tp + rbase + ((s >> 5) + 1) * 34 + (s & 31) + 1;
            float d = 0.f;
#pragma unroll
            for (int dy = -1; dy <= 1; dy++)
#pragma unroll
                for (int dx = -1; dx <= 1; dx++)
                    d += cb[dy * (34 * TPD + 34) + dx * (TPD + 1)];
            Dsh[rl][s] = d * invr;
        }
    }
    __syncthreads();
#pragma unroll
    for (int il = 0; il < 8; il++) {
        int i = i0 + il;
        float* orow = S2 + (size_t)i * LL;
#pragma unroll
        for (int jo = 0; jo < 4; jo++) {
            int j = jo * 256 + tid;
            float acc = 0.f;
#pragma unroll
            for (int k1 = -1; k1 <= 1; k1++) {
                int r = i + k1, s = j + k1;
                if ((unsigned)r < 1024u && (unsigned)s < 1024u)
                    acc += Dsh[il + 1 + k1][s];
            }
            orow[j] = acc;
        }
    }
}

// ---- second diag_fuse (sigma-space) fused with transpose: S3T[q][p] ----
__global__ __launch_bounds__(256) void k_st3t(float* __restrict__ ws, int aff) {
    int bz, p0, q0;
    if (aff) {
        int g = blockIdx.x; bz = g & 15;
        int tile = g >> 4; p0 = (tile >> 4) * 64; q0 = (tile & 15) * 64;
    } else {
        bz = blockIdx.z; p0 = blockIdx.y * 64; q0 = blockIdx.x * 64;
    }
    const float* ib = ws + (size_t)bz * SLAB + OFF_S2;
    float* ob = ws + (size_t)bz * SLAB + OFF_S3T;
    __shared__ float tile[64][65];
    int t = threadIdx.x;
#pragma unroll
    for (int it = 0; it < 16; it++) {
        int e = it * 256 + t;
        int pl = e >> 6, ql = e & 63;
        int p = p0 + pl, q = q0 + ql;
        int sp = ((p & 31) << 5) | (p >> 5);
        int sq = ((q & 31) << 5) | (q >> 5);
        float acc = 0.f;
#pragma unroll
        for (int k = -1; k <= 1; k++) {
            int tp = sp + k, tq = sq + k;
            if ((unsigned)tp < 1024u && (unsigned)tq < 1024u) {
                int row = ((tp & 31) << 5) | (tp >> 5);
                int col = ((tq & 31) << 5) | (tq >> 5);
                acc += ib[(size_t)row * LL + col];
            }
        }
        tile[pl][ql] = acc;
    }
    __syncthreads();
#pragma unroll
    for (int it = 0; it < 16; it++) {
        int e = it * 256 + t;
        int ql = e >> 6, pl = e & 63;
        ob[(size_t)(q0 + ql) * LL + p0 + pl] = tile[pl][ql];
    }
}

// ---- row softmax on S3T, writes bf16 scoreT[q][p] ----
__global__ __launch_bounds__(256) void k_softmax_bf(float* __restrict__ ws, int aff) {
    int bz, q;
    if (aff) {
        int g = blockIdx.x; bz = g & 15;
        q = (g >> 4) * 4 + (threadIdx.x >> 6);
    } else {
        bz = blockIdx.z;
        q = blockIdx.x * 4 + (threadIdx.x >> 6);
    }
    int lane = threadIdx.x & 63;
    const float* row = ws + (size_t)bz * SLAB + OFF_S3T + (size_t)q * LL;
    const float* vb  = ws + (size_t)bz * SLAB + OFF_VALID;
    __bf16* orow = (__bf16*)(ws + (size_t)bz * SLAB + OFF_SCORET) + (size_t)q * LL;

    float4 v[4], vl[4];
#pragma unroll
    for (int i = 0; i < 4; i++) {
        int p = lane * 4 + i * 256;
        float4 s = *(const float4*)(row + p);
        float4 m = *(const float4*)(vb + p);
        v[i] = {s.x * m.x, s.y * m.y, s.z * m.z, s.w * m.w};
        vl[i] = m;
    }
    float mx = -1e30f;
#pragma unroll
    for (int i = 0; i < 4; i++)
        mx = fmaxf(mx, fmaxf(fmaxf(v[i].x, v[i].y), fmaxf(v[i].z, v[i].w)));
#pragma unroll
    for (int k = 1; k < 64; k <<= 1)
        mx = fmaxf(mx, __shfl_xor(mx, k, 64));
    float sum = 0.f;
    float4 e[4];
#pragma unroll
    for (int i = 0; i < 4; i++) {
        e[i].x = __expf(10.f * (v[i].x - mx));
        e[i].y = __expf(10.f * (v[i].y - mx));
        e[i].z = __expf(10.f * (v[i].z - mx));
        e[i].w = __expf(10.f * (v[i].w - mx));
        sum += e[i].x + e[i].y + e[i].z + e[i].w;
    }
#pragma unroll
    for (int k = 1; k < 64; k <<= 1)
        sum += __shfl_xor(sum, k, 64);
    float inv = 1.0f / sum;
#pragma unroll
    for (int i = 0; i < 4; i++) {
        bf16x4 o;
        o[0] = (__bf16)(e[i].x * inv * vl[i].x);
        o[1] = (__bf16)(e[i].y * inv * vl[i].y);
        o[2] = (__bf16)(e[i].z * inv * vl[i].z);
        o[3] = (__bf16)(e[i].w * inv * vl[i].w);
        *(bf16x4*)(orow + lane * 4 + i * 256) = o;
    }
}

// ---- coalesced makeA: block per (channel, batch); LDS image tile ----
__global__ __launch_bounds__(256) void k_makeA(const float* __restrict__ b_o,
                                               float* __restrict__ ws,
                                               int b0, int aff) {
    int c, bz;
    if (aff) { int g = blockIdx.x; bz = g & 15; c = g >> 4; }
    else     { c = blockIdx.x; bz = blockIdx.y; }
    int gb = b0 + bz;
    __shared__ float img[64][65];
    int t = threadIdx.x;
    const float4* src = (const float4*)(b_o + (size_t)(gb * CC + c) * HH * WWI);
#pragma unroll
    for (int it = 0; it < 4; it++) {
        int idx = it * 256 + t;
        float4 v = src[idx];
        int row = idx >> 4, col4 = (idx & 15) * 4;
        img[row][col4] = v.x; img[row][col4 + 1] = v.y;
        img[row][col4 + 2] = v.z; img[row][col4 + 3] = v.w;
    }
    __syncthreads();
    __bf16* Ab = (__bf16*)(ws + (size_t)bz * SLAB + OFF_POOL) + (size_t)c * 9 * LL;
    int py = t >> 3, px4 = (t & 7) * 4;
#pragma unroll
    for (int jy = 0; jy < 3; jy++) {
        int row = 2 * py + jy - 1;
        bool rok = (unsigned)row < 64u;
#pragma unroll
        for (int jx = 0; jx < 3; jx++) {
            bf16x4 o;
#pragma unroll
            for (int e = 0; e < 4; e++) {
                int col = 2 * (px4 + e) + jx - 1;
                float v = (rok && (unsigned)col < 64u) ? img[rok ? row : 0][(unsigned)col < 64u ? col : 0] : 0.f;
                o[e] = (__bf16)v;
            }
            *(bf16x4*)(Ab + (size_t)(jy * 3 + jx) * LL + t * 4) = o;
        }
    }
}

// ---- gather: out[c,oy,ox] = 0.25 * sum of <=4 bf16 W taps ----
__global__ __launch_bounds__(256) void k_gather(const float* __restrict__ ws,
                                                float* __restrict__ outp,
                                                int b0, int aff) {
    int t;
    if (aff) {
        int g = blockIdx.x;
        int bz_ = g & 15;
        t = (bz_ << 19) + (g >> 4) * 256 + threadIdx.x;
    } else {
        t = blockIdx.x * 256 + threadIdx.x;
    }
    int ox = t & 63, oy = (t >> 6) & 63, c = (t >> 12) & 127, bz = t >> 19;
    const __bf16* Wb = (const __bf16*)(ws + (size_t)bz * SLAB + OFF_W);
    int qyA = (oy + 1) >> 1;
    int jyA = (oy & 1) ? 0 : 1;
    int vA  = (qyA < 32);
    int qyB = (oy - 1) >> 1;
    int vB  = (oy & 1);
    int qxA = (ox + 1) >> 1;
    int jxA = (ox & 1) ? 0 : 1;
    int uA  = (qxA < 32);
    int qxB = (ox - 1) >> 1;
    int uB  = (ox & 1);
    const __bf16* base = Wb + (size_t)c * 9 * LL;
    float s = 0.f;
    if (vA && uA) s += (float)base[(size_t)(jyA * 3 + jxA) * LL + qyA * 32 + qxA];
    if (vA && uB) s += (float)base[(size_t)(jyA * 3 + 2)   * LL + qyA * 32 + qxB];
    if (vB && uA) s += (float)base[(size_t)(2 * 3 + jxA)   * LL + qyB * 32 + qxA];
    if (vB && uB) s += (float)base[(size_t)(2 * 3 + 2)     * LL + qyB * 32 + qxB];
    outp[((size_t)((b0 + bz) * CC + c) * HH + oy) * WWI + ox] = 0.25f * s;
}

extern "C" void kernel_launch(void* const* d_in, const int* in_sizes, int n_in,
                              void* d_out, int out_size, void* d_ws, size_t ws_size,
                              hipStream_t stream) {
    (void)in_sizes; (void)n_in; (void)out_size;
    const float* f_o  = (const float*)d_in[0];
    const float* b_o  = (const float*)d_in[1];
    const float* mask = (const float*)d_in[2];
    float* out = (float*)d_out;

    int G = (int)(ws_size / (SLAB * sizeof(float)));   // ~11.9 MB per batch slab
    if (G < 1) G = 1;
    if (G > NB) G = NB;
    float* ws = (float*)d_ws;

    for (int b0 = 0; b0 < NB; b0 += G) {
        int Gc = NB - b0 < G ? NB - b0 : G;
        if (Gc == NB) {
            // XCD-affinity path for the chain; W uses spread decode
            k_prep<<<dim3(512), 256, 0, stream>>>(f_o, b_o, ws, 0, 1);
            k_bnorm_valid<<<dim3(64), 256, 0, stream>>>(ws, mask, 0, 1);
            k_gemm_T_mfma<<<dim3(8, 8, 16), 256, 0, stream>>>(ws, 1);
            k_s12<<<dim3(2048), 256, 0, stream>>>(ws, 1);
            k_st3t<<<dim3(4096), 256, 0, stream>>>(ws, 1);
            k_softmax_bf<<<dim3(4096), 256, 0, stream>>>(ws, 1);
            k_makeA<<<dim3(2048), 256, 0, stream>>>(b_o, ws, 0, 1);
            k_gemm_W192<<<dim3(384), 512, 0, stream>>>(ws);
            k_gather<<<dim3(32768), 256, 0, stream>>>(ws, out, 0, 1);
        } else {
            k_prep<<<dim3(32, Gc), 256, 0, stream>>>(f_o, b_o, ws, b0, 0);
            k_bnorm_valid<<<dim3(Gc * 4), 256, 0, stream>>>(ws, mask, b0, 0);
            k_gemm_T_mfma<<<dim3(8, 8, Gc), 256, 0, stream>>>(ws, 0);
            k_s12<<<dim3(128, Gc), 256, 0, stream>>>(ws, 0);
            k_st3t<<<dim3(16, 16, Gc), 256, 0, stream>>>(ws, 0);
            k_softmax_bf<<<dim3(256, 1, Gc), 256, 0, stream>>>(ws, 0);
            k_makeA<<<dim3(CC, Gc), 256, 0, stream>>>(b_o, ws, b0, 0);
            k_gemm_W_mfma<<<dim3(8, 9, Gc), 256, 0, stream>>>(ws, 0);
            k_gather<<<dim3(Gc * 2048), 256, 0, stream>>>(ws, out, b0, 0);
        }
    }
}

// Round 13
// 346.567 us; speedup vs baseline: 1.1381x; 1.0070x over previous
//
#include <hip/hip_runtime.h>
#include <cmath>

#define CC 128
#define HH 64
#define WWI 64
#define LL 1024
#define NB 16
#define MM 1152          // 128 channels * 9 taps
#define KC 384           // concat K for bf16x3 T-GEMM
#define TPD 1156         // 34*34 padded dim

// per-batch slab layout (floats):
#define SLAB      2977808ul
#define OFF_TP    0
#define OFF_S3T   0
#define OFF_W     0
#define OFF_S2    1336336
#define OFF_SCORET 1336336
#define OFF_POOL  2384912
#define OFF_N2    2974736
#define OFF_BNORM 2975760
#define OFF_VALID 2976784

// halo geometry (zeroing folded into k_gemm_T epilogue)
#define NHROW 132
#define NH1 (NHROW * TPD)
#define NHALO (NH1 + 1024 * NHROW)

// 10-bit half-swap permutation (involution): bs(x) = ((x&31)<<5)|(x>>5)
#define BS(x) ((((x) & 31) << 5) | ((x) >> 5))

typedef __bf16 bf16x8 __attribute__((ext_vector_type(8)));
typedef __bf16 bf16x4 __attribute__((ext_vector_type(4)));
typedef float f32x4 __attribute__((ext_vector_type(4)));

#define GLDS(g, l) __builtin_amdgcn_global_load_lds( \
    (const __attribute__((address_space(1))) unsigned int*)(const void*)(g), \
    (__attribute__((address_space(3))) unsigned int*)(void*)(l), 16, 0, 0)

// K-permutation scheme: the whole sigma chain runs in b = bs(p) index
// space. s12 stores S2 row-permuted (S2sigR[bs(i)][j]); st3t consumes it
// with CONTIGUOUS rows and near-contiguous cols, producing S3T2[q][b];
// bnorm stores valid[] at bs(p); softmax is unchanged (permutation-
// invariant reductions); makeA writes A columns at bs(u) so the W-GEMM
// sums over an identically permuted K on both operands -> W unchanged.

// ---- downsample + transpose (LDS tile) + bf16 hi/lo concat + fused n2 ----
__global__ __launch_bounds__(256) void k_prep(const float* __restrict__ f_o,
                                              const float* __restrict__ b_o,
                                              float* __restrict__ ws,
                                              int b0, int aff) {
    int bz, uy;
    if (aff) { int g = blockIdx.x; bz = g & 15; uy = g >> 4; }
    else     { bz = blockIdx.y; uy = blockIdx.x; }
    int gb = b0 + bz;
    __shared__ float lf[128 * 33];
    __shared__ float lb[128 * 33];
    __shared__ float red[8 * 32];
    int tid = threadIdx.x;
    int ux = tid & 31, co = tid >> 5;
    size_t pix = (size_t)(2 * uy) * WWI + 2 * ux;
    const float* fbp = f_o + (size_t)gb * CC * HH * WWI + pix;
    const float* bbp = b_o + (size_t)gb * CC * HH * WWI + pix;
#pragma unroll
    for (int pass = 0; pass < 16; pass++) {
        int c = pass * 8 + co;
        lf[c * 33 + ux] = fbp[(size_t)c * HH * WWI];
        lb[c * 33 + ux] = bbp[(size_t)c * HH * WWI];
    }
    __syncthreads();
    int ux2 = tid >> 3, cg = (tid & 7) * 16;
    int u = uy * 32 + ux2;
    __bf16* bcat = (__bf16*)(ws + (size_t)bz * SLAB + OFF_POOL) + (size_t)u * KC;
    __bf16* fcat = bcat + 393216;
    float s2 = 0.f;
#pragma unroll
    for (int k = 0; k < 16; k++) {
        int c = cg + k;
        float fv = lf[c * 33 + ux2];
        float bv = lb[c * 33 + ux2];
        __bf16 fhi = (__bf16)fv; __bf16 flo = (__bf16)(fv - (float)fhi);
        __bf16 bhi = (__bf16)bv; __bf16 blo = (__bf16)(bv - (float)bhi);
        bcat[c] = bhi; bcat[128 + c] = bhi; bcat[256 + c] = blo;
        fcat[c] = fhi; fcat[128 + c] = flo; fcat[256 + c] = fhi;
        s2 += bv * bv;
    }
    red[(tid & 7) * 32 + ux2] = s2;
    __syncthreads();
    if (tid < 32) {
        float s = 0.f;
#pragma unroll
        for (int k = 0; k < 8; k++) s += red[k * 32 + tid];
        ws[(size_t)bz * SLAB + OFF_N2 + uy * 32 + tid] = s;
    }
}

__global__ __launch_bounds__(256) void k_bnorm_valid(float* __restrict__ ws,
                                                     const float* __restrict__ mask,
                                                     int b0, int aff) {
    int g = blockIdx.x;
    int bz, pc;
    if (aff) { bz = g & 15; pc = g >> 4; }
    else     { bz = g >> 2; pc = g & 3; }
    int p = pc * 256 + threadIdx.x;
    int gb = b0 + bz;
    int py = p >> 5, px = p & 31;
    const float* mb = mask + (size_t)gb * HH * WWI;
    const float* n2 = ws + (size_t)bz * SLAB + OFF_N2;
    float s = 0.f, msum = 0.f;
#pragma unroll
    for (int dy = -1; dy <= 1; dy++) {
#pragma unroll
        for (int dx = -1; dx <= 1; dx++) {
            int py2 = py + dy, px2 = px + dx;
            if ((unsigned)py2 < 32u && (unsigned)px2 < 32u) {
                s    += n2[(py2 << 5) | px2];
                msum += mb[(2 * py2) * WWI + 2 * px2];
            }
        }
    }
    ws[(size_t)bz * SLAB + OFF_BNORM + p] = fmaxf(sqrtf(s), 1e-4f);
    // valid stored at sigma position bs(p): softmax consumes it b-indexed
    ws[(size_t)bz * SLAB + OFF_VALID + BS(p)] = (msum == 0.0f) ? 1.0f : 0.0f;
}

__device__ __forceinline__ int halo_idx(int k) {
    if (k < 34) return k;
    if (k < 68) return 1122 + (k - 34);
    if (k < 100) return 34 * (k - 100 + 33);
    return 34 * (k - 132 + 33) + 33;
}

// ---- 128x128-tile BK=64 MFMA GEMM core (depth-2 counted vmcnt) ----
template<int KTOT>
__device__ __forceinline__ void gemm_core(const __bf16* __restrict__ Ab,
                                          const __bf16* __restrict__ Bb,
                                          int lda, int ldb, int m0, int n0,
                                          __bf16* As, __bf16* Bs,
                                          f32x4 acc[4][4]) {
    int t = threadIdx.x;
    int lane = t & 63, w = t >> 6;
    int rsub = lane >> 3;
    int g8   = ((lane & 7) ^ (rsub & 7)) * 8;
    int lm = lane & 15, kgf = lane >> 4;
    int wm = (w & 1) * 64, wn = (w >> 1) * 64;

#define ISSUE(kt, buf) do {                                                   \
    int k0_ = (kt) * 64;                                                      \
    _Pragma("unroll")                                                         \
    for (int ci = 0; ci < 4; ci++) {                                          \
        int rb = ci * 32 + w * 8;                                             \
        int r  = rb + rsub;                                                   \
        GLDS(Ab + (size_t)(m0 + r) * lda + k0_ + g8, &As[(buf) + rb * 64]);   \
        GLDS(Bb + (size_t)(n0 + r) * ldb + k0_ + g8, &Bs[(buf) + rb * 64]);   \
    } } while (0)

#define COMPUTE(curoff) do {                                                  \
    _Pragma("unroll")                                                         \
    for (int s2 = 0; s2 < 2; s2++) {                                          \
        bf16x8 af[4], bfr[4];                                                 \
        _Pragma("unroll")                                                     \
        for (int i = 0; i < 4; i++)                                           \
            af[i] = *(const bf16x8*)&As[(curoff) + (wm + i * 16 + lm) * 64 +  \
                                        (((s2 * 4 + kgf) ^ (lm & 7)) * 8)];   \
        _Pragma("unroll")                                                     \
        for (int j = 0; j < 4; j++)                                           \
            bfr[j] = *(const bf16x8*)&Bs[(curoff) + (wn + j * 16 + lm) * 64 + \
                                         (((s2 * 4 + kgf) ^ (lm & 7)) * 8)];  \
        _Pragma("unroll")                                                     \
        for (int i = 0; i < 4; i++)                                           \
            _Pragma("unroll")                                                 \
            for (int j = 0; j < 4; j++)                                       \
                acc[i][j] = __builtin_amdgcn_mfma_f32_16x16x32_bf16(          \
                    af[i], bfr[j], acc[i][j], 0, 0, 0);                       \
    } } while (0)

    const int NIT = KTOT / 64;

    ISSUE(0, 0);
    ISSUE(1, 8192);

#pragma unroll 2
    for (int it = 0; it < NIT - 2; it++) {
        int cur = (it & 1) * 8192;
        asm volatile("s_waitcnt vmcnt(8)" ::: "memory");
        __builtin_amdgcn_sched_barrier(0);
        __builtin_amdgcn_s_barrier();
        COMPUTE(cur);
        __builtin_amdgcn_s_barrier();
        ISSUE(it + 2, cur);
    }
    asm volatile("s_waitcnt vmcnt(8)" ::: "memory");
    __builtin_amdgcn_sched_barrier(0);
    __builtin_amdgcn_s_barrier();
    COMPUTE(((NIT - 2) & 1) * 8192);
    __builtin_amdgcn_s_barrier();
    asm volatile("s_waitcnt vmcnt(0)" ::: "memory");
    __builtin_amdgcn_sched_barrier(0);
    __builtin_amdgcn_s_barrier();
    COMPUTE(((NIT - 1) & 1) * 8192);

#undef ISSUE
#undef COMPUTE
}

// ---- T GEMM (bf16x3 == fp32), padded-4D epilogue + folded halo-zero ----
__global__ __launch_bounds__(256) void k_gemm_T_mfma(float* __restrict__ ws, int swz) {
    int bz, m0, n0;
    if (swz) {
        bz = blockIdx.x + 8 * (blockIdx.z & 1);
        m0 = blockIdx.y * 128;
        n0 = (blockIdx.z >> 1) * 128;
    } else {
        bz = blockIdx.z; m0 = blockIdx.y * 128; n0 = blockIdx.x * 128;
    }
    const __bf16* Ab = (const __bf16*)(ws + (size_t)bz * SLAB + OFF_POOL);
    const __bf16* Bb = Ab + 393216;
    float* Tp = ws + (size_t)bz * SLAB + OFF_TP;
    __shared__ __align__(16) __bf16 As[2 * 128 * 64];
    __shared__ __align__(16) __bf16 Bs[2 * 128 * 64];
    f32x4 acc[4][4];
#pragma unroll
    for (int i = 0; i < 4; i++)
#pragma unroll
        for (int j = 0; j < 4; j++) acc[i][j] = (f32x4)0.0f;
    gemm_core<KC>(Ab, Bb, KC, KC, m0, n0, As, Bs, acc);
    int lane = threadIdx.x & 63, w = threadIdx.x >> 6;
    int lm = lane & 15, kgf = lane >> 4;
    int wm = (w & 1) * 64, wn = (w >> 1) * 64;
#pragma unroll
    for (int i = 0; i < 4; i++) {
#pragma unroll
        for (int r = 0; r < 4; r++) {
            int m = m0 + wm + i * 16 + kgf * 4 + r;
            float* dst = Tp + (size_t)(((m >> 5) + 1) * 34 + (m & 31) + 1) * TPD;
#pragma unroll
            for (int j = 0; j < 4; j++) {
                int v = n0 + wn + j * 16 + lm;
                dst[((v >> 5) + 1) * 34 + (v & 31) + 1] = acc[i][j][r];
            }
        }
    }
    // folded zerohalo: the 64 blocks of this batch cooperatively zero the
    // NHALO halo cells (disjoint from interior stores; s12 runs next launch)
    int cb = (m0 >> 7) * 8 + (n0 >> 7);            // [0,64) per batch
    for (int h = cb * 256 + (int)threadIdx.x; h < NHALO; h += 64 * 256) {
        if (h < NH1) {
            int R = halo_idx(h / TPD);
            Tp[(size_t)R * TPD + (h % TPD)] = 0.f;
        } else {
            int t2 = h - NH1;
            int ir = t2 / NHROW;
            int R  = 34 * (1 + (ir >> 5)) + 1 + (ir & 31);
            int C  = halo_idx(t2 % NHROW);
            Tp[(size_t)R * TPD + C] = 0.f;
        }
    }
}

// ---- W GEMM, 192x256 tile, 512 threads / 8 waves (measured best: 61.8us)
__global__ __launch_bounds__(512, 2) void k_gemm_W192(float* __restrict__ ws) {
    int d = blockIdx.x;                 // 384 blocks
    int logical = (d & 7) * 48 + (d >> 3);
    int bz  = logical / 24;
    int t24 = logical % 24;
    int m0 = (t24 >> 2) * 192;          // 6 M-tiles exact
    int n0 = (t24 & 3) * 256;
    const __bf16* Ab = (const __bf16*)(ws + (size_t)bz * SLAB + OFF_POOL);
    const __bf16* Bb = (const __bf16*)(ws + (size_t)bz * SLAB + OFF_SCORET);
    __bf16* Wb = (__bf16*)(ws + (size_t)bz * SLAB + OFF_W);
    __shared__ __align__(16) __bf16 As[2 * 192 * 64];   // 48 KiB
    __shared__ __align__(16) __bf16 Bs[2 * 256 * 64];   // 64 KiB

    int t = threadIdx.x;
    int lane = t & 63, w = t >> 6;
    int rsub = lane >> 3;
    int g8   = ((lane & 7) ^ (rsub & 7)) * 8;
    int lm = lane & 15, kgf = lane >> 4;
    int wr = (w >> 2) * 96;             // wave M-offset (0/96)
    int wc = (w & 3) * 64;              // wave N-offset (0/64/128/192)

    f32x4 acc[6][4];
#pragma unroll
    for (int i = 0; i < 6; i++)
#pragma unroll
        for (int j = 0; j < 4; j++) acc[i][j] = (f32x4)0.0f;

#define WSTAGE(nbA, nbB, k1_) do {                                            \
    _Pragma("unroll")                                                         \
    for (int ci = 0; ci < 3; ci++) {                                          \
        int rb = ci * 64 + w * 8;                                             \
        GLDS(Ab + (size_t)(m0 + rb + rsub) * LL + (k1_) + g8,                 \
             &As[(nbA) + rb * 64]);                                           \
    }                                                                         \
    _Pragma("unroll")                                                         \
    for (int ci = 0; ci < 4; ci++) {                                          \
        int rb = ci * 64 + w * 8;                                             \
        GLDS(Bb + (size_t)(n0 + rb + rsub) * LL + (k1_) + g8,                 \
             &Bs[(nbB) + rb * 64]);                                           \
    } } while (0)

#define RD_A(mh, boA) do {                                                    \
    _Pragma("unroll")                                                         \
    for (int mi = 0; mi < 3; mi++)                                            \
        _Pragma("unroll")                                                     \
        for (int ks = 0; ks < 2; ks++)                                        \
            af[mi][ks] = *(const bf16x8*)&As[(boA) +                          \
                (wr + (mh) * 48 + mi * 16 + lm) * 64 +                        \
                (((ks * 4 + kgf) ^ (lm & 7)) * 8)];                           \
    } while (0)

#define RD_B(njlo, boB) do {                                                  \
    _Pragma("unroll")                                                         \
    for (int nj = 0; nj < 2; nj++)                                            \
        _Pragma("unroll")                                                     \
        for (int ks = 0; ks < 2; ks++)                                        \
            bfr[(njlo) + nj][ks] = *(const bf16x8*)&Bs[(boB) +                \
                (wc + ((njlo) + nj) * 16 + lm) * 64 +                         \
                (((ks * 4 + kgf) ^ (lm & 7)) * 8)];                           \
    } while (0)

#define QMFMA(mb, njlo) do {                                                  \
    __builtin_amdgcn_s_setprio(1);                                            \
    _Pragma("unroll")                                                         \
    for (int ks = 0; ks < 2; ks++)                                            \
        _Pragma("unroll")                                                     \
        for (int mi = 0; mi < 3; mi++)                                        \
            _Pragma("unroll")                                                 \
            for (int nj = 0; nj < 2; nj++)                                    \
                acc[(mb) + mi][(njlo) + nj] =                                 \
                    __builtin_amdgcn_mfma_f32_16x16x32_bf16(                  \
                        af[mi][ks], bfr[(njlo) + nj][ks],                     \
                        acc[(mb) + mi][(njlo) + nj], 0, 0, 0);                \
    __builtin_amdgcn_s_setprio(0);                                            \
    } while (0)

    WSTAGE(0, 0, 0);
    asm volatile("s_waitcnt vmcnt(0)" ::: "memory");
    __builtin_amdgcn_sched_barrier(0);
    __builtin_amdgcn_s_barrier();

#pragma unroll 2
    for (int kt = 0; kt < 16; kt++) {
        int boA = (kt & 1) * 12288, boB = (kt & 1) * 16384;
        int nbA = boA ^ 12288, nbB = boB ^ 16384;
        bf16x8 af[3][2], bfr[4][2];
        if (kt < 15) WSTAGE(nbA, nbB, (kt + 1) * 64);
        RD_A(0, boA);
        RD_B(0, boB);
        QMFMA(0, 0);
        RD_B(2, boB);
        QMFMA(0, 2);
        RD_A(1, boA);
        QMFMA(3, 2);
        QMFMA(3, 0);
        if (kt < 15) {
            asm volatile("s_waitcnt vmcnt(0)" ::: "memory");
            __builtin_amdgcn_sched_barrier(0);
            __builtin_amdgcn_s_barrier();
        }
    }

#undef WSTAGE
#undef RD_A
#undef RD_B
#undef QMFMA

#pragma unroll
    for (int mf = 0; mf < 6; mf++) {
#pragma unroll
        for (int r = 0; r < 4; r++) {
            int m = m0 + wr + mf * 16 + kgf * 4 + r;   // always < 1152
            __bf16* dst = Wb + (size_t)m * LL + n0 + wc + lm;
#pragma unroll
            for (int nj = 0; nj < 4; nj++)
                dst[nj * 16] = (__bf16)acc[mf][nj][r];
        }
    }
}

// ---- W[m,q] GEMM 128-tile fallback (Gc<16 path) ----
__global__ __launch_bounds__(256) void k_gemm_W_mfma(float* __restrict__ ws, int swz) {
    int bz, m0, n0;
    if (swz) {
        bz = blockIdx.x + 8 * (blockIdx.z & 1);
        m0 = blockIdx.y * 128;
        n0 = (blockIdx.z >> 1) * 128;
    } else {
        bz = blockIdx.z; m0 = blockIdx.y * 128; n0 = blockIdx.x * 128;
    }
    const __bf16* Ab = (const __bf16*)(ws + (size_t)bz * SLAB + OFF_POOL);
    const __bf16* Bb = (const __bf16*)(ws + (size_t)bz * SLAB + OFF_SCORET);
    __bf16* Wb = (__bf16*)(ws + (size_t)bz * SLAB + OFF_W);
    __shared__ __align__(16) __bf16 As[2 * 128 * 64];
    __shared__ __align__(16) __bf16 Bs[2 * 128 * 64];
    f32x4 acc[4][4];
#pragma unroll
    for (int i = 0; i < 4; i++)
#pragma unroll
        for (int j = 0; j < 4; j++) acc[i][j] = (f32x4)0.0f;
    gemm_core<LL>(Ab, Bb, LL, LL, m0, n0, As, Bs, acc);
    int lane = threadIdx.x & 63, w = threadIdx.x >> 6;
    int lm = lane & 15, kgf = lane >> 4;
    int wm = (w & 1) * 64, wn = (w >> 1) * 64;
#pragma unroll
    for (int i = 0; i < 4; i++) {
#pragma unroll
        for (int r = 0; r < 4; r++) {
            int m = m0 + wm + i * 16 + kgf * 4 + r;
            __bf16* dst = Wb + (size_t)m * LL + n0 + wn + lm;
#pragma unroll
            for (int j = 0; j < 4; j++)
                dst[j * 16] = (__bf16)acc[i][j][r];
        }
    }
}

// ---- fused st1+st2 (padded T); writes S2 ROW-PERMUTED: S2sigR[bs(i)][j] ----
__global__ __launch_bounds__(256) void k_s12(float* __restrict__ ws, int aff) {
    int bz, i0;
    if (aff) { int g = blockIdx.x; bz = g & 15; i0 = (g >> 4) * 8; }
    else     { bz = blockIdx.y; i0 = blockIdx.x * 8; }
    const float* Tp = ws + (size_t)bz * SLAB + OFF_TP;
    const float* bn = ws + (size_t)bz * SLAB + OFF_BNORM;
    float* S2 = ws + (size_t)bz * SLAB + OFF_S2;
    __shared__ float Dsh[10][1024];
    int tid = threadIdx.x;
    for (int rl = 0; rl < 10; rl++) {
        int r = i0 - 1 + rl;
        if ((unsigned)r >= 1024u) continue;
        float invr = 1.0f / bn[r];
        size_t rbase = (size_t)(((r >> 5) + 1) * 34 + (r & 31) + 1) * TPD;
#pragma unroll
        for (int so = 0; so < 4; so++) {
            int s = so * 256 + tid;
            const float* cb = Tp + rbase + ((s >> 5) + 1) * 34 + (s & 31) + 1;
            float d = 0.f;
#pragma unroll
            for (int dy = -1; dy <= 1; dy++)
#pragma unroll
                for (int dx = -1; dx <= 1; dx++)
                    d += cb[dy * (34 * TPD + 34) + dx * (TPD + 1)];
            Dsh[rl][s] = d * invr;
        }
    }
    __syncthreads();
#pragma unroll
    for (int il = 0; il < 8; il++) {
        int i = i0 + il;
        float* orow = S2 + (size_t)BS(i) * LL;         // row-permuted store
#pragma unroll
        for (int jo = 0; jo < 4; jo++) {
            int j = jo * 256 + tid;
            float acc = 0.f;
#pragma unroll
            for (int k1 = -1; k1 <= 1; k1++) {
                int r = i + k1, s = j + k1;
                if ((unsigned)r < 1024u && (unsigned)s < 1024u)
                    acc += Dsh[il + 1 + k1][s];
            }
            orow[j] = acc;
        }
    }
}

// ---- second diag_fuse in sigma space: S3T2[q][b] = S3T[q][bs(b)] ----
// Input S2sigR (row-permuted). Read = S2sigR[(b+k)*LL + bs(bs(q)+k)]:
// rows contiguous; cols = q (k=0) and ~q+-32 (k=+-1) -> coalesced lanes.
__global__ __launch_bounds__(256) void k_st3t(float* __restrict__ ws, int aff) {
    int bz, b0, q0;
    if (aff) {
        int g = blockIdx.x; bz = g & 15;
        int tile_ = g >> 4; b0 = (tile_ >> 4) * 64; q0 = (tile_ & 15) * 64;
    } else {
        bz = blockIdx.z; b0 = blockIdx.y * 64; q0 = blockIdx.x * 64;
    }
    const float* ib = ws + (size_t)bz * SLAB + OFF_S2;   // S2sigR
    float* ob = ws + (size_t)bz * SLAB + OFF_S3T;        // S3T2
    __shared__ float tile[64][65];
    int t = threadIdx.x;
#pragma unroll
    for (int it = 0; it < 16; it++) {
        int e = it * 256 + t;
        int bl = e >> 6, ql = e & 63;      // q fastest: coalesced reads
        int b = b0 + bl, q = q0 + ql;
        int sq = BS(q);
        float acc = 0.f;
#pragma unroll
        for (int k = -1; k <= 1; k++) {
            int tp = b + k, tq = sq + k;
            if ((unsigned)tp < 1024u && (unsigned)tq < 1024u)
                acc += ib[(size_t)tp * LL + BS(tq)];
        }
        tile[bl][ql] = acc;
    }
    __syncthreads();
#pragma unroll
    for (int it = 0; it < 16; it++) {
        int e = it * 256 + t;
        int ql = e >> 6, bl = e & 63;      // b fastest: coalesced writes
        ob[(size_t)(q0 + ql) * LL + b0 + bl] = tile[bl][ql];
    }
}

// ---- row softmax on S3T2, writes bf16 scoreT2[q][b] (b-space throughout) ----
__global__ __launch_bounds__(256) void k_softmax_bf(float* __restrict__ ws, int aff) {
    int bz, q;
    if (aff) {
        int g = blockIdx.x; bz = g & 15;
        q = (g >> 4) * 4 + (threadIdx.x >> 6);
    } else {
        bz = blockIdx.z;
        q = blockIdx.x * 4 + (threadIdx.x >> 6);
    }
    int lane = threadIdx.x & 63;
    const float* row = ws + (size_t)bz * SLAB + OFF_S3T + (size_t)q * LL;
    const float* vb  = ws + (size_t)bz * SLAB + OFF_VALID;   // sigma-indexed
    __bf16* orow = (__bf16*)(ws + (size_t)bz * SLAB + OFF_SCORET) + (size_t)q * LL;

    float4 v[4], vl[4];
#pragma unroll
    for (int i = 0; i < 4; i++) {
        int p = lane * 4 + i * 256;
        float4 s = *(const float4*)(row + p);
        float4 m = *(const float4*)(vb + p);
        v[i] = {s.x * m.x, s.y * m.y, s.z * m.z, s.w * m.w};
        vl[i] = m;
    }
    float mx = -1e30f;
#pragma unroll
    for (int i = 0; i < 4; i++)
        mx = fmaxf(mx, fmaxf(fmaxf(v[i].x, v[i].y), fmaxf(v[i].z, v[i].w)));
#pragma unroll
    for (int k = 1; k < 64; k <<= 1)
        mx = fmaxf(mx, __shfl_xor(mx, k, 64));
    float sum = 0.f;
    float4 e[4];
#pragma unroll
    for (int i = 0; i < 4; i++) {
        e[i].x = __expf(10.f * (v[i].x - mx));
        e[i].y = __expf(10.f * (v[i].y - mx));
        e[i].z = __expf(10.f * (v[i].z - mx));
        e[i].w = __expf(10.f * (v[i].w - mx));
        sum += e[i].x + e[i].y + e[i].z + e[i].w;
    }
#pragma unroll
    for (int k = 1; k < 64; k <<= 1)
        sum += __shfl_xor(sum, k, 64);
    float inv = 1.0f / sum;
#pragma unroll
    for (int i = 0; i < 4; i++) {
        bf16x4 o;
        o[0] = (__bf16)(e[i].x * inv * vl[i].x);
        o[1] = (__bf16)(e[i].y * inv * vl[i].y);
        o[2] = (__bf16)(e[i].z * inv * vl[i].z);
        o[3] = (__bf16)(e[i].w * inv * vl[i].w);
        *(bf16x4*)(orow + lane * 4 + i * 256) = o;
    }
}

// ---- makeA in sigma-K: A2[m][b] = A[m][bs(b)] (px/py roles swapped) ----
__global__ __launch_bounds__(256) void k_makeA(const float* __restrict__ b_o,
                                               float* __restrict__ ws,
                                               int b0, int aff) {
    int c, bz;
    if (aff) { int g = blockIdx.x; bz = g & 15; c = g >> 4; }
    else     { c = blockIdx.x; bz = blockIdx.y; }
    int gb = b0 + bz;
    __shared__ float img[64][65];
    int t = threadIdx.x;
    const float4* src = (const float4*)(b_o + (size_t)(gb * CC + c) * HH * WWI);
#pragma unroll
    for (int it = 0; it < 4; it++) {
        int idx = it * 256 + t;
        float4 v = src[idx];
        int row = idx >> 4, col4 = (idx & 15) * 4;
        img[row][col4] = v.x; img[row][col4 + 1] = v.y;
        img[row][col4 + 2] = v.z; img[row][col4 + 3] = v.w;
    }
    __syncthreads();
    __bf16* Ab = (__bf16*)(ws + (size_t)bz * SLAB + OFF_POOL) + (size_t)c * 9 * LL;
    // column b = t*4+e: pixel u = bs(b) -> py = b&31 = (t&7)*4+e, px = b>>5 = t>>3
    int px = t >> 3, py4 = (t & 7) * 4;
#pragma unroll
    for (int jy = 0; jy < 3; jy++) {
#pragma unroll
        for (int jx = 0; jx < 3; jx++) {
            int col = 2 * px + jx - 1;
            bool cok = (unsigned)col < 64u;
            bf16x4 o;
#pragma unroll
            for (int e = 0; e < 4; e++) {
                int row = 2 * (py4 + e) + jy - 1;
                float v = (cok && (unsigned)row < 64u)
                            ? img[(unsigned)row < 64u ? row : 0][cok ? col : 0] : 0.f;
                o[e] = (__bf16)v;
            }
            *(bf16x4*)(Ab + (size_t)(jy * 3 + jx) * LL + t * 4) = o;
        }
    }
}

// ---- gather: out[c,oy,ox] = 0.25 * sum of <=4 bf16 W taps (W unchanged) ----
__global__ __launch_bounds__(256) void k_gather(const float* __restrict__ ws,
                                                float* __restrict__ outp,
                                                int b0, int aff) {
    int t;
    if (aff) {
        int g = blockIdx.x;
        int bz_ = g & 15;
        t = (bz_ << 19) + (g >> 4) * 256 + threadIdx.x;
    } else {
        t = blockIdx.x * 256 + threadIdx.x;
    }
    int ox = t & 63, oy = (t >> 6) & 63, c = (t >> 12) & 127, bz = t >> 19;
    const __bf16* Wb = (const __bf16*)(ws + (size_t)bz * SLAB + OFF_W);
    int qyA = (oy + 1) >> 1;
    int jyA = (oy & 1) ? 0 : 1;
    int vA  = (qyA < 32);
    int qyB = (oy - 1) >> 1;
    int vB  = (oy & 1);
    int qxA = (ox + 1) >> 1;
    int jxA = (ox & 1) ? 0 : 1;
    int uA  = (qxA < 32);
    int qxB = (ox - 1) >> 1;
    int uB  = (ox & 1);
    const __bf16* base = Wb + (size_t)c * 9 * LL;
    float s = 0.f;
    if (vA && uA) s += (float)base[(size_t)(jyA * 3 + jxA) * LL + qyA * 32 + qxA];
    if (vA && uB) s += (float)base[(size_t)(jyA * 3 + 2)   * LL + qyA * 32 + qxB];
    if (vB && uA) s += (float)base[(size_t)(2 * 3 + jxA)   * LL + qyB * 32 + qxA];
    if (vB && uB) s += (float)base[(size_t)(2 * 3 + 2)     * LL + qyB * 32 + qxB];
    outp[((size_t)((b0 + bz) * CC + c) * HH + oy) * WWI + ox] = 0.25f * s;
}

extern "C" void kernel_launch(void* const* d_in, const int* in_sizes, int n_in,
                              void* d_out, int out_size, void* d_ws, size_t ws_size,
                              hipStream_t stream) {
    (void)in_sizes; (void)n_in; (void)out_size;
    const float* f_o  = (const float*)d_in[0];
    const float* b_o  = (const float*)d_in[1];
    const float* mask = (const float*)d_in[2];
    float* out = (float*)d_out;

    int G = (int)(ws_size / (SLAB * sizeof(float)));   // ~11.9 MB per batch slab
    if (G < 1) G = 1;
    if (G > NB) G = NB;
    float* ws = (float*)d_ws;

    for (int b0 = 0; b0 < NB; b0 += G) {
        int Gc = NB - b0 < G ? NB - b0 : G;
        if (Gc == NB) {
            // XCD-affinity path for the chain; W uses spread decode
            k_prep<<<dim3(512), 256, 0, stream>>>(f_o, b_o, ws, 0, 1);
            k_bnorm_valid<<<dim3(64), 256, 0, stream>>>(ws, mask, 0, 1);
            k_gemm_T_mfma<<<dim3(8, 8, 16), 256, 0, stream>>>(ws, 1);
            k_s12<<<dim3(2048), 256, 0, stream>>>(ws, 1);
            k_st3t<<<dim3(4096), 256, 0, stream>>>(ws, 1);
            k_softmax_bf<<<dim3(4096), 256, 0, stream>>>(ws, 1);
            k_makeA<<<dim3(2048), 256, 0, stream>>>(b_o, ws, 0, 1);
            k_gemm_W192<<<dim3(384), 512, 0, stream>>>(ws);
            k_gather<<<dim3(32768), 256, 0, stream>>>(ws, out, 0, 1);
        } else {
            k_prep<<<dim3(32, Gc), 256, 0, stream>>>(f_o, b_o, ws, b0, 0);
            k_bnorm_valid<<<dim3(Gc * 4), 256, 0, stream>>>(ws, mask, b0, 0);
            k_gemm_T_mfma<<<dim3(8, 8, Gc), 256, 0, stream>>>(ws, 0);
            k_s12<<<dim3(128, Gc), 256, 0, stream>>>(ws, 0);
            k_st3t<<<dim3(16, 16, Gc), 256, 0, stream>>>(ws, 0);
            k_softmax_bf<<<dim3(256, 1, Gc), 256, 0, stream>>>(ws, 0);
            k_makeA<<<dim3(CC, Gc), 256, 0, stream>>>(b_o, ws, b0, 0);
            k_gemm_W_mfma<<<dim3(8, 9, Gc), 256, 0, stream>>>(ws, 0);
            k_gather<<<dim3(Gc * 2048), 256, 0, stream>>>(ws, out, b0, 0);
        }
    }
}